// Round 3
// baseline (1168.260 us; speedup 1.0000x reference)
//
#include <hip/hip_runtime.h>
#include <math.h>

#define Hd 128
#define Rr 3
#define Ll 4
#define NPW 16   // nodes (M-rows) per wave

typedef float f32x4 __attribute__((ext_vector_type(4)));
typedef short s16x8 __attribute__((ext_vector_type(8)));

__device__ __forceinline__ unsigned short f2bf(float f){
    unsigned u = __float_as_uint(f);
    return (unsigned short)((u + 0x7FFFu + ((u >> 16) & 1u)) >> 16);
}
__device__ __forceinline__ float bf2f(unsigned short h){
    return __uint_as_float(((unsigned)h) << 16);
}
__device__ __forceinline__ void split8(float4 a, float4 b, s16x8& hi, s16x8& lo){
    float v[8] = {a.x, a.y, a.z, a.w, b.x, b.y, b.z, b.w};
    #pragma unroll
    for (int j = 0; j < 8; ++j){
        unsigned short h = f2bf(v[j]);
        hi[j] = (short)h;
        lo[j] = (short)f2bf(v[j] - bf2f(h));
    }
}
__device__ __forceinline__ int lower_bound_i32(const int* __restrict__ a, int n, int key){
    int lo = 0, hi = n;
    while (lo < hi){
        int mid = (lo + hi) >> 1;
        if (a[mid] < key) lo = mid + 1; else hi = mid;
    }
    return lo;
}

// ---- McT = out_w @ wv (folded), bc = out_w @ bv + out_b  (verified r1/r2) ----
__global__ void fold_proj_kernel(const float* __restrict__ in_proj_w,
                                 const float* __restrict__ in_proj_b,
                                 const float* __restrict__ out_w,
                                 const float* __restrict__ out_b,
                                 float* __restrict__ McT,
                                 float* __restrict__ bc)
{
    const int i = blockIdx.x;   // k index
    const int j = threadIdx.x;  // n index
    float acc = 0.f;
    for (int k = 0; k < Hd; ++k)
        acc = fmaf(out_w[j * Hd + k], in_proj_w[(2 * Hd + k) * Hd + i], acc);
    McT[i * Hd + j] = acc;
    if (i == 0){
        float b = out_b[j];
        for (int k = 0; k < Hd; ++k)
            b = fmaf(out_w[j * Hd + k], in_proj_b[2 * Hd + k], b);
        bc[j] = b;
    }
}

// ---- split weights into bf16 hi/lo MFMA B-fragments (verified r2) ----
// frag elem j of lane l at (mat,kc,nc):  W[kc*32 + (l>>4)*8 + j][nc*16 + (l&15)]
__global__ void pack_kernel(const float* __restrict__ r_whh, const float* __restrict__ u_whh,
                            const float* __restrict__ r_wxh, const float* __restrict__ u_wxh,
                            const float* __restrict__ c_whh, const float* __restrict__ c_wxh,
                            const float* __restrict__ McT,
                            unsigned short* __restrict__ whi, unsigned short* __restrict__ wlo)
{
    const int mat  = blockIdx.y;   // 0..6
    const int tile = blockIdx.x;   // 0..31 : kc = tile>>3, nc = tile&7
    const int l    = threadIdx.x;  // 0..63
    const float* W;
    switch (mat){
        case 0: W = r_whh; break;  case 1: W = u_whh; break;
        case 2: W = r_wxh; break;  case 3: W = u_wxh; break;
        case 4: W = c_whh; break;  case 5: W = c_wxh; break;
        default: W = McT;
    }
    const int kc = tile >> 3, nc = tile & 7;
    const int kbase = kc * 32 + (l >> 4) * 8;
    const int n = nc * 16 + (l & 15);
    const size_t obase = ((size_t)(mat * 32 + tile) * 64 + l) * 8;
    #pragma unroll
    for (int j = 0; j < 8; ++j){
        float v = W[(kbase + j) * Hd + n];
        unsigned short h = f2bf(v);
        whi[obase + j] = h;
        wlo[obase + j] = f2bf(v - bf2f(h));
    }
}

#define BFRAG(arr, mat, kc, nc) (*(const s16x8*)((arr) + ((((mat) * 32 + (kc) * 8 + (nc)) * 64 + l) * 8)))

#define MM3(acc, AH, AL, BH, BL)                                              \
    acc = __builtin_amdgcn_mfma_f32_16x16x32_bf16(AH, BH, acc, 0, 0, 0);      \
    acc = __builtin_amdgcn_mfma_f32_16x16x32_bf16(AL, BH, acc, 0, 0, 0);      \
    acc = __builtin_amdgcn_mfma_f32_16x16x32_bf16(AH, BL, acc, 0, 0, 0);

__global__ __launch_bounds__(256, 2) void gru_mfma_kernel(
    const float* __restrict__ x_rank,
    const int* __restrict__ valid_idx, int nv,
    const float* __restrict__ r_b, const float* __restrict__ u_b, const float* __restrict__ c_b,
    const unsigned short* __restrict__ whi, const unsigned short* __restrict__ wlo,
    const float* __restrict__ bc,
    float* __restrict__ out, int N)
{
    // per-wave transpose scratch (no cross-wave sharing -> no data barriers)
    __shared__ __align__(16) float S_all[4][NPW][132];
    __shared__ float bias_s[4][Hd];
    __shared__ int lo_all[4][NPW];
    __shared__ int hi_all[4][NPW];

    const int tid = threadIdx.x;
    const int wid = tid >> 6;
    const int l   = tid & 63;
    const int lr  = l & 15;
    const int lg  = l >> 4;
    const int n0  = (blockIdx.x * 4 + wid) * NPW;

    float (*S)[132] = S_all[wid];
    int* loL = lo_all[wid];
    int* hiL = hi_all[wid];

    if (tid < Hd){
        bias_s[0][tid] = r_b[tid];
        bias_s[1][tid] = u_b[tid];
        bias_s[2][tid] = c_b[tid];
        bias_s[3][tid] = bc[tid];
    }
    __syncthreads();

    // persistent register state
    f32x4 hD[8];                 // h in D-layout: row lg*4+i, col nc*16+lr
    s16x8 ahi[4], alo[4];        // h A-frags (k = kc*32 + lg*8 + j), row lr
    #pragma unroll
    for (int nc = 0; nc < 8; ++nc) hD[nc] = (f32x4){0.f, 0.f, 0.f, 0.f};
    #pragma unroll
    for (int kc = 0; kc < 4; ++kc){ ahi[kc] = (s16x8)0; alo[kc] = (s16x8)0; }

    s16x8 xhi[4], xlo[4];
    s16x8 rhhi[4], rhlo[4];
    f32x4 zD[8];

    #pragma unroll 1
    for (int t = 0; t < Rr; ++t){
        __syncthreads();   // bound wave drift (L1 B-frag reuse); no data dependence

        // ---- output-row ranges ----
        if (l < NPW){
            int n = n0 + l, lo = 0, hi = 0;
            if (n < N){
                int F = (n * Rr + t) * Ll;
                lo = lower_bound_i32(valid_idx, nv, F);
                hi = lower_bound_i32(valid_idx, nv, F + Ll);
            }
            loL[l] = lo; hiL[l] = hi;
        }

        // ---- x A-frags ----
        {
            int nn = n0 + lr; if (nn > N - 1) nn = N - 1;
            const float* xp = x_rank + ((size_t)nn * Rr + t) * Hd;
            #pragma unroll
            for (int kc = 0; kc < 4; ++kc){
                float4 a = *(const float4*)(xp + kc * 32 + lg * 8);
                float4 b = *(const float4*)(xp + kc * 32 + lg * 8 + 4);
                split8(a, b, xhi[kc], xlo[kc]);
            }
        }

        // ---- r/z phase: acc = h@Whh + x@Wxh ; write r*h to S, keep z in regs ----
        #pragma unroll
        for (int nc = 0; nc < 8; ++nc){
            f32x4 ar = (f32x4){0.f, 0.f, 0.f, 0.f};
            f32x4 az = (f32x4){0.f, 0.f, 0.f, 0.f};
            #pragma unroll
            for (int kc = 0; kc < 4; ++kc){
                s16x8 b0h = BFRAG(whi, 0, kc, nc), b0l = BFRAG(wlo, 0, kc, nc);
                MM3(ar, ahi[kc], alo[kc], b0h, b0l);
                s16x8 b2h = BFRAG(whi, 2, kc, nc), b2l = BFRAG(wlo, 2, kc, nc);
                MM3(ar, xhi[kc], xlo[kc], b2h, b2l);
                s16x8 b1h = BFRAG(whi, 1, kc, nc), b1l = BFRAG(wlo, 1, kc, nc);
                MM3(az, ahi[kc], alo[kc], b1h, b1l);
                s16x8 b3h = BFRAG(whi, 3, kc, nc), b3l = BFRAG(wlo, 3, kc, nc);
                MM3(az, xhi[kc], xlo[kc], b3h, b3l);
            }
            const float rbc = bias_s[0][nc * 16 + lr];
            const float ubc = bias_s[1][nc * 16 + lr];
            #pragma unroll
            for (int i = 0; i < 4; ++i){
                float r = 1.f / (1.f + __expf(-(ar[i] + rbc)));
                float z = 1.f / (1.f + __expf(-(az[i] + ubc)));
                zD[nc][i] = z;
                S[lg * 4 + i][nc * 16 + lr] = r * hD[nc][i];
            }
        }

        // ---- (r*h) A-frags from S (same-wave LDS order guarantees visibility) ----
        #pragma unroll
        for (int kc = 0; kc < 4; ++kc){
            const float* p = &S[lr][kc * 32 + lg * 8];
            split8(*(const float4*)p, *(const float4*)(p + 4), rhhi[kc], rhlo[kc]);
        }

        // ---- c phase + h update (in regs); write h' to S ----
        #pragma unroll
        for (int nc = 0; nc < 8; ++nc){
            f32x4 ac = (f32x4){0.f, 0.f, 0.f, 0.f};
            #pragma unroll
            for (int kc = 0; kc < 4; ++kc){
                s16x8 b4h = BFRAG(whi, 4, kc, nc), b4l = BFRAG(wlo, 4, kc, nc);
                MM3(ac, rhhi[kc], rhlo[kc], b4h, b4l);
                s16x8 b5h = BFRAG(whi, 5, kc, nc), b5l = BFRAG(wlo, 5, kc, nc);
                MM3(ac, xhi[kc], xlo[kc], b5h, b5l);
            }
            const float cbc = bias_s[2][nc * 16 + lr];
            #pragma unroll
            for (int i = 0; i < 4; ++i){
                float e = __expf(2.f * (ac[i] + cbc));
                float c = 1.f - 2.f / (e + 1.f);     // tanh, saturates correctly
                float ho = hD[nc][i];
                float hn = ho + zD[nc][i] * (c - ho);
                hD[nc][i] = hn;
                S[lg * 4 + i][nc * 16 + lr] = hn;
            }
        }

        // ---- h' A-frags (also next t's h-frags) ----
        #pragma unroll
        for (int kc = 0; kc < 4; ++kc){
            const float* p = &S[lr][kc * 32 + lg * 8];
            split8(*(const float4*)p, *(const float4*)(p + 4), ahi[kc], alo[kc]);
        }

        // ---- o phase + scatter ----
        int lor[4], hir[4];
        #pragma unroll
        for (int i = 0; i < 4; ++i){
            lor[i] = loL[lg * 4 + i];
            hir[i] = hiL[lg * 4 + i];
        }
        #pragma unroll
        for (int nc = 0; nc < 8; ++nc){
            f32x4 ao = (f32x4){0.f, 0.f, 0.f, 0.f};
            #pragma unroll
            for (int kc = 0; kc < 4; ++kc){
                s16x8 b6h = BFRAG(whi, 6, kc, nc), b6l = BFRAG(wlo, 6, kc, nc);
                MM3(ao, ahi[kc], alo[kc], b6h, b6l);
            }
            const float obc = bias_s[3][nc * 16 + lr];
            #pragma unroll
            for (int i = 0; i < 4; ++i){
                float v = ao[i] + obc;
                const int col = nc * 16 + lr;
                for (int rr = lor[i]; rr < hir[i]; ++rr)
                    out[(size_t)rr * Hd + col] = v;
            }
        }
    }
}

__global__ void he_order_kernel(const int* __restrict__ he_order,
                                float* __restrict__ out_tail, int nv)
{
    const int i = blockIdx.x * 256 + threadIdx.x;
    if (i < nv) out_tail[i] = (float)he_order[i];
}

extern "C" void kernel_launch(void* const* d_in, const int* in_sizes, int n_in,
                              void* d_out, int out_size, void* d_ws, size_t ws_size,
                              hipStream_t stream)
{
    const float* x_rank    = (const float*)d_in[0];
    // d_in[1] he_features, d_in[2] he_idx: dead (softmax over singleton axis == 1)
    const int*   valid_idx = (const int*)d_in[3];
    const int*   he_order  = (const int*)d_in[4];
    const float* r_whh = (const float*)d_in[5];
    const float* r_wxh = (const float*)d_in[6];
    const float* r_b   = (const float*)d_in[7];
    const float* u_whh = (const float*)d_in[8];
    const float* u_wxh = (const float*)d_in[9];
    const float* u_b   = (const float*)d_in[10];
    const float* c_whh = (const float*)d_in[11];
    const float* c_wxh = (const float*)d_in[12];
    const float* c_b   = (const float*)d_in[13];
    const float* in_proj_w = (const float*)d_in[14];
    const float* in_proj_b = (const float*)d_in[15];
    const float* out_w     = (const float*)d_in[16];
    const float* out_b     = (const float*)d_in[17];

    const int nv = in_sizes[3];
    const int N  = in_sizes[0] / (Rr * Hd);

    // workspace layout
    float* McT = (float*)d_ws;                         // 16384 f32
    float* bc  = McT + Hd * Hd;                        // 128 f32
    unsigned short* whi = (unsigned short*)(bc + Hd);  // 7*16384 u16
    unsigned short* wlo = whi + 7 * 16384;             // 7*16384 u16

    float* out_f    = (float*)d_out;
    float* out_tail = out_f + (size_t)nv * Hd;

    fold_proj_kernel<<<Hd, Hd, 0, stream>>>(in_proj_w, in_proj_b, out_w, out_b, McT, bc);
    pack_kernel<<<dim3(32, 7), 64, 0, stream>>>(r_whh, u_whh, r_wxh, u_wxh, c_whh, c_wxh,
                                                McT, whi, wlo);

    const int nodes_per_block = 4 * NPW;  // 64
    const int nblocks = (N + nodes_per_block - 1) / nodes_per_block;  // 469
    gru_mfma_kernel<<<nblocks, 256, 0, stream>>>(
        x_rank, valid_idx, nv, r_b, u_b, c_b, whi, wlo, bc, out_f, N);

    he_order_kernel<<<(nv + 255) / 256, 256, 0, stream>>>(he_order, out_tail, nv);
}

// Round 4
// 577.960 us; speedup vs baseline: 2.0214x; 2.0214x over previous
//
#include <hip/hip_runtime.h>
#include <math.h>

#define Hd 128
#define Rr 3
#define Ll 4
#define NPW 16   // nodes (M-rows) per wave

typedef float f32x4 __attribute__((ext_vector_type(4)));
typedef short s16x8 __attribute__((ext_vector_type(8)));

__device__ __forceinline__ unsigned short f2bf(float f){
    unsigned u = __float_as_uint(f);
    return (unsigned short)((u + 0x7FFFu + ((u >> 16) & 1u)) >> 16);
}
__device__ __forceinline__ float bf2f(unsigned short h){
    return __uint_as_float(((unsigned)h) << 16);
}
__device__ __forceinline__ void split8(const float* p, s16x8& hi, s16x8& lo){
    float4 a = *(const float4*)p;
    float4 b = *(const float4*)(p + 4);
    float v[8] = {a.x, a.y, a.z, a.w, b.x, b.y, b.z, b.w};
    #pragma unroll
    for (int j = 0; j < 8; ++j){
        unsigned short h = f2bf(v[j]);
        hi[j] = (short)h;
        lo[j] = (short)f2bf(v[j] - bf2f(h));
    }
}
__device__ __forceinline__ int lower_bound_i32(const int* __restrict__ a, int n, int key){
    int lo = 0, hi = n;
    while (lo < hi){
        int mid = (lo + hi) >> 1;
        if (a[mid] < key) lo = mid + 1; else hi = mid;
    }
    return lo;
}

// ---- McT = out_w @ wv (folded), bc = out_w @ bv + out_b  (verified r1-r3) ----
__global__ void fold_proj_kernel(const float* __restrict__ in_proj_w,
                                 const float* __restrict__ in_proj_b,
                                 const float* __restrict__ out_w,
                                 const float* __restrict__ out_b,
                                 float* __restrict__ McT,
                                 float* __restrict__ bc)
{
    const int i = blockIdx.x;   // k index
    const int j = threadIdx.x;  // n index
    float acc = 0.f;
    for (int k = 0; k < Hd; ++k)
        acc = fmaf(out_w[j * Hd + k], in_proj_w[(2 * Hd + k) * Hd + i], acc);
    McT[i * Hd + j] = acc;
    if (i == 0){
        float b = out_b[j];
        for (int k = 0; k < Hd; ++k)
            b = fmaf(out_w[j * Hd + k], in_proj_b[2 * Hd + k], b);
        bc[j] = b;
    }
}

// ---- quantize weights to bf16 MFMA B-fragments (hi only, 2-split scheme) ----
// frag elem j of lane l at (mat,kc,nc):  W[kc*32 + (l>>4)*8 + j][nc*16 + (l&15)]
__global__ void pack_kernel(const float* __restrict__ r_whh, const float* __restrict__ u_whh,
                            const float* __restrict__ r_wxh, const float* __restrict__ u_wxh,
                            const float* __restrict__ c_whh, const float* __restrict__ c_wxh,
                            const float* __restrict__ McT,
                            unsigned short* __restrict__ whi)
{
    const int mat  = blockIdx.y;   // 0..6
    const int tile = blockIdx.x;   // 0..31 : kc = tile>>3, nc = tile&7
    const int l    = threadIdx.x;  // 0..63
    const float* W;
    switch (mat){
        case 0: W = r_whh; break;  case 1: W = u_whh; break;
        case 2: W = r_wxh; break;  case 3: W = u_wxh; break;
        case 4: W = c_whh; break;  case 5: W = c_wxh; break;
        default: W = McT;
    }
    const int kc = tile >> 3, nc = tile & 7;
    const int kbase = kc * 32 + (l >> 4) * 8;
    const int n = nc * 16 + (l & 15);
    const size_t obase = ((size_t)(mat * 32 + tile) * 64 + l) * 8;
    #pragma unroll
    for (int j = 0; j < 8; ++j)
        whi[obase + j] = f2bf(W[(kbase + j) * Hd + n]);
}

#define BFRAG(arr, mat, kc, nc) (*(const s16x8*)((arr) + ((((mat) * 32 + (kc) * 8 + (nc)) * 64 + l) * 8)))

#define MM2(acc, AH, AL, BH)                                              \
    acc = __builtin_amdgcn_mfma_f32_16x16x32_bf16(AH, BH, acc, 0, 0, 0);  \
    acc = __builtin_amdgcn_mfma_f32_16x16x32_bf16(AL, BH, acc, 0, 0, 0);

__global__ __launch_bounds__(256) __attribute__((amdgpu_waves_per_eu(2)))
void gru_mfma_kernel(
    const float* __restrict__ x_rank,
    const int* __restrict__ valid_idx, int nv,
    const float* __restrict__ r_b, const float* __restrict__ u_b, const float* __restrict__ c_b,
    const unsigned short* __restrict__ whi,
    const float* __restrict__ bc,
    float* __restrict__ out, int N)
{
    // per-wave LDS: h state + r*h transpose scratch (no cross-wave sharing)
    __shared__ __align__(16) float Sh_all[4][NPW][132];
    __shared__ __align__(16) float Sr_all[4][NPW][132];
    __shared__ float bias_s[4][Hd];
    __shared__ int lo_all[4][NPW];
    __shared__ int hi_all[4][NPW];

    const int tid = threadIdx.x;
    const int wid = tid >> 6;
    const int l   = tid & 63;
    const int lr  = l & 15;
    const int lg  = l >> 4;
    const int n0  = (blockIdx.x * 4 + wid) * NPW;

    float (*Sh)[132] = Sh_all[wid];
    float (*Sr)[132] = Sr_all[wid];
    int* loL = lo_all[wid];
    int* hiL = hi_all[wid];

    if (tid < Hd){
        bias_s[0][tid] = r_b[tid];
        bias_s[1][tid] = u_b[tid];
        bias_s[2][tid] = c_b[tid];
        bias_s[3][tid] = bc[tid];
    }
    // zero own h tile (t=0 state); own-wave writes, read only by own wave
    {
        float* hz = (float*)Sh;
        for (int i = l; i < NPW * 132; i += 64) hz[i] = 0.f;
    }

    // persistent register state (lean): h-frags, x-frags, z
    s16x8 ahi[4], alo[4];     // h A-frags (row lr, k = kc*32+lg*8+j); h(t=0)=0
    #pragma unroll
    for (int kc = 0; kc < 4; ++kc){ ahi[kc] = (s16x8)0; alo[kc] = (s16x8)0; }
    s16x8 xhi[4], xlo[4];
    s16x8 rhhi[4], rhlo[4];
    f32x4 zD[8];

    #pragma unroll 1
    for (int t = 0; t < Rr; ++t){
        __syncthreads();   // covers bias/zero init at t=0; aligns waves for L1 B-frag reuse

        // ---- output-row ranges ----
        if (l < NPW){
            int n = n0 + l, lo = 0, hi = 0;
            if (n < N){
                int F = (n * Rr + t) * Ll;
                lo = lower_bound_i32(valid_idx, nv, F);
                hi = lower_bound_i32(valid_idx, nv, F + Ll);
            }
            loL[l] = lo; hiL[l] = hi;
        }

        // ---- x A-frags (node = n0+lr, clamped; OOB rows never stored) ----
        {
            int nn = n0 + lr; if (nn > N - 1) nn = N - 1;
            const float* xp = x_rank + ((size_t)nn * Rr + t) * Hd;
            #pragma unroll
            for (int kc = 0; kc < 4; ++kc)
                split8(xp + kc * 32 + lg * 8, xhi[kc], xlo[kc]);
        }

        // ---- r/z phase: acc = h@Whh + x@Wxh; write r*h to Sr, z to regs ----
        #pragma unroll
        for (int nc = 0; nc < 8; ++nc){
            f32x4 ar = (f32x4){0.f, 0.f, 0.f, 0.f};
            f32x4 az = (f32x4){0.f, 0.f, 0.f, 0.f};
            #pragma unroll
            for (int kc = 0; kc < 4; ++kc){
                s16x8 b0 = BFRAG(whi, 0, kc, nc);
                MM2(ar, ahi[kc], alo[kc], b0);
                s16x8 b2 = BFRAG(whi, 2, kc, nc);
                MM2(ar, xhi[kc], xlo[kc], b2);
                s16x8 b1 = BFRAG(whi, 1, kc, nc);
                MM2(az, ahi[kc], alo[kc], b1);
                s16x8 b3 = BFRAG(whi, 3, kc, nc);
                MM2(az, xhi[kc], xlo[kc], b3);
            }
            const float rbc = bias_s[0][nc * 16 + lr];
            const float ubc = bias_s[1][nc * 16 + lr];
            #pragma unroll
            for (int i = 0; i < 4; ++i){
                const int row = lg * 4 + i, col = nc * 16 + lr;
                float ho = Sh[row][col];
                float r = 1.f / (1.f + __expf(-(ar[i] + rbc)));
                float z = 1.f / (1.f + __expf(-(az[i] + ubc)));
                zD[nc][i] = z;
                Sr[row][col] = r * ho;
            }
        }

        // ---- (r*h) A-frags (same-wave LDS in-order: writes above are visible) ----
        #pragma unroll
        for (int kc = 0; kc < 4; ++kc)
            split8(&Sr[lr][kc * 32 + lg * 8], rhhi[kc], rhlo[kc]);

        // ---- c phase + h update (h' written back to Sh) ----
        #pragma unroll
        for (int nc = 0; nc < 8; ++nc){
            f32x4 ac = (f32x4){0.f, 0.f, 0.f, 0.f};
            #pragma unroll
            for (int kc = 0; kc < 4; ++kc){
                s16x8 b4 = BFRAG(whi, 4, kc, nc);
                MM2(ac, rhhi[kc], rhlo[kc], b4);
                s16x8 b5 = BFRAG(whi, 5, kc, nc);
                MM2(ac, xhi[kc], xlo[kc], b5);
            }
            const float cbc = bias_s[2][nc * 16 + lr];
            #pragma unroll
            for (int i = 0; i < 4; ++i){
                const int row = lg * 4 + i, col = nc * 16 + lr;
                float e = __expf(2.f * (ac[i] + cbc));
                float c = 1.f - 2.f / (e + 1.f);     // tanh, saturates correctly
                float ho = Sh[row][col];
                Sh[row][col] = ho + zD[nc][i] * (c - ho);
            }
        }

        // ---- h' A-frags: serve o-phase now AND r/z of next t ----
        #pragma unroll
        for (int kc = 0; kc < 4; ++kc)
            split8(&Sh[lr][kc * 32 + lg * 8], ahi[kc], alo[kc]);

        // ---- o phase + scatter through valid_idx runs ----
        int lor[4], hir[4];
        #pragma unroll
        for (int i = 0; i < 4; ++i){
            lor[i] = loL[lg * 4 + i];
            hir[i] = hiL[lg * 4 + i];
        }
        #pragma unroll
        for (int nc = 0; nc < 8; ++nc){
            f32x4 ao = (f32x4){0.f, 0.f, 0.f, 0.f};
            #pragma unroll
            for (int kc = 0; kc < 4; ++kc){
                s16x8 b6 = BFRAG(whi, 6, kc, nc);
                MM2(ao, ahi[kc], alo[kc], b6);
            }
            const float obc = bias_s[3][nc * 16 + lr];
            #pragma unroll
            for (int i = 0; i < 4; ++i){
                float v = ao[i] + obc;
                const int col = nc * 16 + lr;
                for (int rr = lor[i]; rr < hir[i]; ++rr)
                    out[(size_t)rr * Hd + col] = v;
            }
        }
    }
}

__global__ void he_order_kernel(const int* __restrict__ he_order,
                                float* __restrict__ out_tail, int nv)
{
    const int i = blockIdx.x * 256 + threadIdx.x;
    if (i < nv) out_tail[i] = (float)he_order[i];
}

extern "C" void kernel_launch(void* const* d_in, const int* in_sizes, int n_in,
                              void* d_out, int out_size, void* d_ws, size_t ws_size,
                              hipStream_t stream)
{
    const float* x_rank    = (const float*)d_in[0];
    // d_in[1] he_features, d_in[2] he_idx: dead (softmax over singleton axis == 1)
    const int*   valid_idx = (const int*)d_in[3];
    const int*   he_order  = (const int*)d_in[4];
    const float* r_whh = (const float*)d_in[5];
    const float* r_wxh = (const float*)d_in[6];
    const float* r_b   = (const float*)d_in[7];
    const float* u_whh = (const float*)d_in[8];
    const float* u_wxh = (const float*)d_in[9];
    const float* u_b   = (const float*)d_in[10];
    const float* c_whh = (const float*)d_in[11];
    const float* c_wxh = (const float*)d_in[12];
    const float* c_b   = (const float*)d_in[13];
    const float* in_proj_w = (const float*)d_in[14];
    const float* in_proj_b = (const float*)d_in[15];
    const float* out_w     = (const float*)d_in[16];
    const float* out_b     = (const float*)d_in[17];

    const int nv = in_sizes[3];
    const int N  = in_sizes[0] / (Rr * Hd);

    // workspace layout
    float* McT = (float*)d_ws;                         // 16384 f32
    float* bc  = McT + Hd * Hd;                        // 128 f32
    unsigned short* whi = (unsigned short*)(bc + Hd);  // 7*16384 u16

    float* out_f    = (float*)d_out;
    float* out_tail = out_f + (size_t)nv * Hd;

    fold_proj_kernel<<<Hd, Hd, 0, stream>>>(in_proj_w, in_proj_b, out_w, out_b, McT, bc);
    pack_kernel<<<dim3(32, 7), 64, 0, stream>>>(r_whh, u_whh, r_wxh, u_wxh, c_whh, c_wxh,
                                                McT, whi);

    const int nodes_per_block = 4 * NPW;  // 64
    const int nblocks = (N + nodes_per_block - 1) / nodes_per_block;  // 469
    gru_mfma_kernel<<<nblocks, 256, 0, stream>>>(
        x_rank, valid_idx, nv, r_b, u_b, c_b, whi, bc, out_f, N);

    he_order_kernel<<<(nv + 255) / 256, 256, 0, stream>>>(he_order, out_tail, nv);
}

// Round 5
// 489.892 us; speedup vs baseline: 2.3847x; 1.1798x over previous
//
#include <hip/hip_runtime.h>
#include <math.h>

#define Hd 128
#define Rr 3
#define Ll 4
#define NPW 16   // nodes (M-rows) per wave

typedef float f32x4 __attribute__((ext_vector_type(4)));
typedef short s16x8 __attribute__((ext_vector_type(8)));

__device__ __forceinline__ unsigned short f2bf(float f){
    unsigned u = __float_as_uint(f);
    return (unsigned short)((u + 0x7FFFu + ((u >> 16) & 1u)) >> 16);
}
__device__ __forceinline__ float bf2f(unsigned short h){
    return __uint_as_float(((unsigned)h) << 16);
}
__device__ __forceinline__ void split8(const float* p, s16x8& hi, s16x8& lo){
    float4 a = *(const float4*)p;
    float4 b = *(const float4*)(p + 4);
    float v[8] = {a.x, a.y, a.z, a.w, b.x, b.y, b.z, b.w};
    #pragma unroll
    for (int j = 0; j < 8; ++j){
        unsigned short h = f2bf(v[j]);
        hi[j] = (short)h;
        lo[j] = (short)f2bf(v[j] - bf2f(h));
    }
}
__device__ __forceinline__ int lower_bound_i32(const int* __restrict__ a, int n, int key){
    int lo = 0, hi = n;
    while (lo < hi){
        int mid = (lo + hi) >> 1;
        if (a[mid] < key) lo = mid + 1; else hi = mid;
    }
    return lo;
}

// ---- McT = out_w @ wv (folded), bc = out_w @ bv + out_b  (verified r1-r4) ----
__global__ void fold_proj_kernel(const float* __restrict__ in_proj_w,
                                 const float* __restrict__ in_proj_b,
                                 const float* __restrict__ out_w,
                                 const float* __restrict__ out_b,
                                 float* __restrict__ McT,
                                 float* __restrict__ bc)
{
    const int i = blockIdx.x;   // k index
    const int j = threadIdx.x;  // n index
    float acc = 0.f;
    for (int k = 0; k < Hd; ++k)
        acc = fmaf(out_w[j * Hd + k], in_proj_w[(2 * Hd + k) * Hd + i], acc);
    McT[i * Hd + j] = acc;
    if (i == 0){
        float b = out_b[j];
        for (int k = 0; k < Hd; ++k)
            b = fmaf(out_w[j * Hd + k], in_proj_b[2 * Hd + k], b);
        bc[j] = b;
    }
}

// ---- quantize weights to bf16 MFMA B-fragments (verified r4) ----
// frag elem j of lane l at (mat,kc,nc):  W[kc*32 + (l>>4)*8 + j][nc*16 + (l&15)]
__global__ void pack_kernel(const float* __restrict__ r_whh, const float* __restrict__ u_whh,
                            const float* __restrict__ r_wxh, const float* __restrict__ u_wxh,
                            const float* __restrict__ c_whh, const float* __restrict__ c_wxh,
                            const float* __restrict__ McT,
                            unsigned short* __restrict__ whi)
{
    const int mat  = blockIdx.y;   // 0..6
    const int tile = blockIdx.x;   // 0..31 : kc = tile>>3, nc = tile&7
    const int l    = threadIdx.x;  // 0..63
    const float* W;
    switch (mat){
        case 0: W = r_whh; break;  case 1: W = u_whh; break;
        case 2: W = r_wxh; break;  case 3: W = u_wxh; break;
        case 4: W = c_whh; break;  case 5: W = c_wxh; break;
        default: W = McT;
    }
    const int kc = tile >> 3, nc = tile & 7;
    const int kbase = kc * 32 + (l >> 4) * 8;
    const int n = nc * 16 + (l & 15);
    const size_t obase = ((size_t)(mat * 32 + tile) * 64 + l) * 8;
    #pragma unroll
    for (int j = 0; j < 8; ++j)
        whi[obase + j] = f2bf(W[(kbase + j) * Hd + n]);
}

#define BFRAG(mat, kc, nc) (*(const s16x8*)(whi + ((((mat) * 32 + (kc) * 8 + (nc)) * 64 + l) * 8)))

#define MM2(acc, AH, AL, BH)                                              \
    acc = __builtin_amdgcn_mfma_f32_16x16x32_bf16(AH, BH, acc, 0, 0, 0);  \
    acc = __builtin_amdgcn_mfma_f32_16x16x32_bf16(AL, BH, acc, 0, 0, 0);

__global__ __launch_bounds__(256, 1) void gru_mfma_kernel(
    const float* __restrict__ x_rank,
    const int* __restrict__ valid_idx, int nv,
    const float* __restrict__ r_b, const float* __restrict__ u_b, const float* __restrict__ c_b,
    const unsigned short* __restrict__ whi,
    const float* __restrict__ bc,
    float* __restrict__ out, int N)
{
    // per-wave LDS: h state + transpose scratch (no cross-wave data sharing)
    __shared__ __align__(16) float Sh_all[4][NPW][132];
    __shared__ __align__(16) float Sr_all[4][NPW][132];
    __shared__ float bias_s[4][Hd];
    __shared__ int lo_all[4][NPW];
    __shared__ int hi_all[4][NPW];

    const int tid = threadIdx.x;
    const int wid = tid >> 6;
    const int l   = tid & 63;
    const int lr  = l & 15;
    const int lg  = l >> 4;
    const int n0  = (blockIdx.x * 4 + wid) * NPW;

    float (*Sh)[132] = Sh_all[wid];
    float (*Sr)[132] = Sr_all[wid];
    int* loL = lo_all[wid];
    int* hiL = hi_all[wid];

    if (tid < Hd){
        bias_s[0][tid] = r_b[tid];
        bias_s[1][tid] = u_b[tid];
        bias_s[2][tid] = c_b[tid];
        bias_s[3][tid] = bc[tid];
    }
    // zero own h tile (t=0 state); own-wave writes, own-wave reads
    {
        float* hz = (float*)Sh;
        for (int i = l; i < NPW * 132; i += 64) hz[i] = 0.f;
    }

    s16x8 ahi[4], alo[4];     // h A-frags (row lr, k = kc*32+lg*8+j); h(t=0)=0
    #pragma unroll
    for (int kc = 0; kc < 4; ++kc){ ahi[kc] = (s16x8)0; alo[kc] = (s16x8)0; }
    s16x8 xhi[4], xlo[4];
    s16x8 rhhi[4], rhlo[4];
    f32x4 zD[8];

    #pragma unroll 1
    for (int t = 0; t < Rr; ++t){
        __syncthreads();   // t=0: bias init visible; also keeps waves aligned for L1 B-reuse

        // ---- output-row ranges ----
        if (l < NPW){
            int n = n0 + l, lo = 0, hi = 0;
            if (n < N){
                int F = (n * Rr + t) * Ll;
                lo = lower_bound_i32(valid_idx, nv, F);
                hi = lower_bound_i32(valid_idx, nv, F + Ll);
            }
            loL[l] = lo; hiL[l] = hi;
        }

        // ---- x A-frags (node = n0+lr, clamped; OOB rows never stored) ----
        {
            int nn = n0 + lr; if (nn > N - 1) nn = N - 1;
            const float* xp = x_rank + ((size_t)nn * Rr + t) * Hd;
            #pragma unroll
            for (int kc = 0; kc < 4; ++kc)
                split8(xp + kc * 32 + lg * 8, xhi[kc], xlo[kc]);
        }
        __builtin_amdgcn_sched_barrier(0);

        // ---- Phase R: ar = h@r_whh + x@r_wxh ; Sr = sigmoid(ar+rb) * h ----
        #pragma unroll
        for (int nc = 0; nc < 8; ++nc){
            f32x4 ar = (f32x4){0.f, 0.f, 0.f, 0.f};
            #pragma unroll
            for (int kc = 0; kc < 4; ++kc){
                s16x8 b0 = BFRAG(0, kc, nc);
                MM2(ar, ahi[kc], alo[kc], b0);
                s16x8 b2 = BFRAG(2, kc, nc);
                MM2(ar, xhi[kc], xlo[kc], b2);
            }
            const float rbc = bias_s[0][nc * 16 + lr];
            #pragma unroll
            for (int i = 0; i < 4; ++i){
                const int row = lg * 4 + i, col = nc * 16 + lr;
                float r = 1.f / (1.f + __expf(-(ar[i] + rbc)));
                Sr[row][col] = r * Sh[row][col];
            }
            if (nc & 1) __builtin_amdgcn_sched_barrier(0);
        }

        // ---- Phase Z: az = h@u_whh + x@u_wxh ; zD = sigmoid(az+ub) ----
        #pragma unroll
        for (int nc = 0; nc < 8; ++nc){
            f32x4 az = (f32x4){0.f, 0.f, 0.f, 0.f};
            #pragma unroll
            for (int kc = 0; kc < 4; ++kc){
                s16x8 b1 = BFRAG(1, kc, nc);
                MM2(az, ahi[kc], alo[kc], b1);
                s16x8 b3 = BFRAG(3, kc, nc);
                MM2(az, xhi[kc], xlo[kc], b3);
            }
            const float ubc = bias_s[1][nc * 16 + lr];
            #pragma unroll
            for (int i = 0; i < 4; ++i)
                zD[nc][i] = 1.f / (1.f + __expf(-(az[i] + ubc)));
            if (nc & 1) __builtin_amdgcn_sched_barrier(0);
        }

        // ---- (r*h) A-frags (same-wave LDS in-order: R-phase writes visible) ----
        #pragma unroll
        for (int kc = 0; kc < 4; ++kc)
            split8(&Sr[lr][kc * 32 + lg * 8], rhhi[kc], rhlo[kc]);
        __builtin_amdgcn_sched_barrier(0);

        // ---- Phase C: ac = (r*h)@c_whh + x@c_wxh ; h' = h + z*(tanh(ac+cb)-h) ----
        #pragma unroll
        for (int nc = 0; nc < 8; ++nc){
            f32x4 ac = (f32x4){0.f, 0.f, 0.f, 0.f};
            #pragma unroll
            for (int kc = 0; kc < 4; ++kc){
                s16x8 b4 = BFRAG(4, kc, nc);
                MM2(ac, rhhi[kc], rhlo[kc], b4);
                s16x8 b5 = BFRAG(5, kc, nc);
                MM2(ac, xhi[kc], xlo[kc], b5);
            }
            const float cbc = bias_s[2][nc * 16 + lr];
            #pragma unroll
            for (int i = 0; i < 4; ++i){
                const int row = lg * 4 + i, col = nc * 16 + lr;
                float e = __expf(2.f * (ac[i] + cbc));
                float c = 1.f - 2.f / (e + 1.f);     // tanh, saturates correctly
                float ho = Sh[row][col];
                Sh[row][col] = ho + zD[nc][i] * (c - ho);
            }
            if (nc & 1) __builtin_amdgcn_sched_barrier(0);
        }

        // ---- h' A-frags: serve Phase O now AND Phase R of next t ----
        #pragma unroll
        for (int kc = 0; kc < 4; ++kc)
            split8(&Sh[lr][kc * 32 + lg * 8], ahi[kc], alo[kc]);
        __builtin_amdgcn_sched_barrier(0);

        // ---- Phase O: ao = h'@McT ; scatter through valid_idx runs ----
        int lor[4], hir[4];
        #pragma unroll
        for (int i = 0; i < 4; ++i){
            lor[i] = loL[lg * 4 + i];
            hir[i] = hiL[lg * 4 + i];
        }
        #pragma unroll
        for (int nc = 0; nc < 8; ++nc){
            f32x4 ao = (f32x4){0.f, 0.f, 0.f, 0.f};
            #pragma unroll
            for (int kc = 0; kc < 4; ++kc){
                s16x8 b6 = BFRAG(6, kc, nc);
                MM2(ao, ahi[kc], alo[kc], b6);
            }
            const float obc = bias_s[3][nc * 16 + lr];
            #pragma unroll
            for (int i = 0; i < 4; ++i){
                float v = ao[i] + obc;
                const int col = nc * 16 + lr;
                for (int rr = lor[i]; rr < hir[i]; ++rr)
                    out[(size_t)rr * Hd + col] = v;
            }
            if (nc & 1) __builtin_amdgcn_sched_barrier(0);
        }
    }
}

__global__ void he_order_kernel(const int* __restrict__ he_order,
                                float* __restrict__ out_tail, int nv)
{
    const int i = blockIdx.x * 256 + threadIdx.x;
    if (i < nv) out_tail[i] = (float)he_order[i];
}

extern "C" void kernel_launch(void* const* d_in, const int* in_sizes, int n_in,
                              void* d_out, int out_size, void* d_ws, size_t ws_size,
                              hipStream_t stream)
{
    const float* x_rank    = (const float*)d_in[0];
    // d_in[1] he_features, d_in[2] he_idx: dead (softmax over singleton axis == 1)
    const int*   valid_idx = (const int*)d_in[3];
    const int*   he_order  = (const int*)d_in[4];
    const float* r_whh = (const float*)d_in[5];
    const float* r_wxh = (const float*)d_in[6];
    const float* r_b   = (const float*)d_in[7];
    const float* u_whh = (const float*)d_in[8];
    const float* u_wxh = (const float*)d_in[9];
    const float* u_b   = (const float*)d_in[10];
    const float* c_whh = (const float*)d_in[11];
    const float* c_wxh = (const float*)d_in[12];
    const float* c_b   = (const float*)d_in[13];
    const float* in_proj_w = (const float*)d_in[14];
    const float* in_proj_b = (const float*)d_in[15];
    const float* out_w     = (const float*)d_in[16];
    const float* out_b     = (const float*)d_in[17];

    const int nv = in_sizes[3];
    const int N  = in_sizes[0] / (Rr * Hd);

    // workspace layout
    float* McT = (float*)d_ws;                         // 16384 f32
    float* bc  = McT + Hd * Hd;                        // 128 f32
    unsigned short* whi = (unsigned short*)(bc + Hd);  // 7*16384 u16

    float* out_f    = (float*)d_out;
    float* out_tail = out_f + (size_t)nv * Hd;

    fold_proj_kernel<<<Hd, Hd, 0, stream>>>(in_proj_w, in_proj_b, out_w, out_b, McT, bc);
    pack_kernel<<<dim3(32, 7), 64, 0, stream>>>(r_whh, u_whh, r_wxh, u_wxh, c_whh, c_wxh,
                                                McT, whi);

    const int nodes_per_block = 4 * NPW;  // 64
    const int nblocks = (N + nodes_per_block - 1) / nodes_per_block;  // 469
    gru_mfma_kernel<<<nblocks, 256, 0, stream>>>(
        x_rank, valid_idx, nv, r_b, u_b, c_b, whi, bc, out_f, N);

    he_order_kernel<<<(nv + 255) / 256, 256, 0, stream>>>(he_order, out_tail, nv);
}

// Round 6
// 453.040 us; speedup vs baseline: 2.5787x; 1.0813x over previous
//
#include <hip/hip_runtime.h>
#include <math.h>

#define Hd 128
#define Rr 3
#define Ll 4
#define NPW 16   // nodes (M-rows) per wave

typedef float f32x4 __attribute__((ext_vector_type(4)));
typedef short s16x8 __attribute__((ext_vector_type(8)));

__device__ __forceinline__ unsigned short f2bf(float f){
    unsigned u = __float_as_uint(f);
    return (unsigned short)((u + 0x7FFFu + ((u >> 16) & 1u)) >> 16);
}
__device__ __forceinline__ float bf2f(unsigned short h){
    return __uint_as_float(((unsigned)h) << 16);
}
__device__ __forceinline__ void split8(const float* p, s16x8& hi, s16x8& lo){
    float4 a = *(const float4*)p;
    float4 b = *(const float4*)(p + 4);
    float v[8] = {a.x, a.y, a.z, a.w, b.x, b.y, b.z, b.w};
    #pragma unroll
    for (int j = 0; j < 8; ++j){
        unsigned short h = f2bf(v[j]);
        hi[j] = (short)h;
        lo[j] = (short)f2bf(v[j] - bf2f(h));
    }
}
__device__ __forceinline__ int lower_bound_i32(const int* __restrict__ a, int n, int key){
    int lo = 0, hi = n;
    while (lo < hi){
        int mid = (lo + hi) >> 1;
        if (a[mid] < key) lo = mid + 1; else hi = mid;
    }
    return lo;
}

// ---- McT = out_w @ wv (folded), bc = out_w @ bv + out_b  (verified r1-r5) ----
__global__ void fold_proj_kernel(const float* __restrict__ in_proj_w,
                                 const float* __restrict__ in_proj_b,
                                 const float* __restrict__ out_w,
                                 const float* __restrict__ out_b,
                                 float* __restrict__ McT,
                                 float* __restrict__ bc)
{
    const int i = blockIdx.x;   // k index
    const int j = threadIdx.x;  // n index
    float acc = 0.f;
    for (int k = 0; k < Hd; ++k)
        acc = fmaf(out_w[j * Hd + k], in_proj_w[(2 * Hd + k) * Hd + i], acc);
    McT[i * Hd + j] = acc;
    if (i == 0){
        float b = out_b[j];
        for (int k = 0; k < Hd; ++k)
            b = fmaf(out_w[j * Hd + k], in_proj_b[2 * Hd + k], b);
        bc[j] = b;
    }
}

// ---- quantize weights to bf16 MFMA B-fragments (verified r4/r5) ----
// frag elem j of lane l at (mat,kc,nc):  W[kc*32 + (l>>4)*8 + j][nc*16 + (l&15)]
__global__ void pack_kernel(const float* __restrict__ r_whh, const float* __restrict__ u_whh,
                            const float* __restrict__ r_wxh, const float* __restrict__ u_wxh,
                            const float* __restrict__ c_whh, const float* __restrict__ c_wxh,
                            const float* __restrict__ McT,
                            unsigned short* __restrict__ whi)
{
    const int mat  = blockIdx.y;   // 0..6
    const int tile = blockIdx.x;   // 0..31 : kc = tile>>3, nc = tile&7
    const int l    = threadIdx.x;  // 0..63
    const float* W;
    switch (mat){
        case 0: W = r_whh; break;  case 1: W = u_whh; break;
        case 2: W = r_wxh; break;  case 3: W = u_wxh; break;
        case 4: W = c_whh; break;  case 5: W = c_wxh; break;
        default: W = McT;
    }
    const int kc = tile >> 3, nc = tile & 7;
    const int kbase = kc * 32 + (l >> 4) * 8;
    const int n = nc * 16 + (l & 15);
    const size_t obase = ((size_t)(mat * 32 + tile) * 64 + l) * 8;
    #pragma unroll
    for (int j = 0; j < 8; ++j)
        whi[obase + j] = f2bf(W[(kbase + j) * Hd + n]);
}

#define BFRAG(mat, kc, nc) (*(const s16x8*)(whi + ((((mat) * 32 + (kc) * 8 + (nc)) * 64 + l) * 8)))

#define MM2(acc, AH, AL, BH)                                              \
    acc = __builtin_amdgcn_mfma_f32_16x16x32_bf16(AH, BH, acc, 0, 0, 0);  \
    acc = __builtin_amdgcn_mfma_f32_16x16x32_bf16(AL, BH, acc, 0, 0, 0);

__global__ __launch_bounds__(256, 1) void gru_mfma_kernel(
    const float* __restrict__ x_rank,
    const int* __restrict__ valid_idx, int nv,
    const float* __restrict__ r_b, const float* __restrict__ u_b, const float* __restrict__ c_b,
    const unsigned short* __restrict__ whi,
    const float* __restrict__ bc,
    float* __restrict__ out, int N)
{
    // per-wave LDS: h state + multi-purpose scratch (rh -> c -> out staging)
    __shared__ __align__(16) float Sh_all[4][NPW][132];
    __shared__ __align__(16) float Sr_all[4][NPW][132];
    __shared__ float bias_s[4][Hd];
    __shared__ int lo_all[4][NPW];
    __shared__ int hi_all[4][NPW];

    const int tid = threadIdx.x;
    const int wid = tid >> 6;
    const int l   = tid & 63;
    const int lr  = l & 15;
    const int lg  = l >> 4;
    const int n0  = (blockIdx.x * 4 + wid) * NPW;

    float (*Sh)[132] = Sh_all[wid];
    float (*Sr)[132] = Sr_all[wid];
    int* loL = lo_all[wid];
    int* hiL = hi_all[wid];

    if (tid < Hd){
        bias_s[0][tid] = r_b[tid];
        bias_s[1][tid] = u_b[tid];
        bias_s[2][tid] = c_b[tid];
        bias_s[3][tid] = bc[tid];
    }
    // zero own h tile (t=0 state); own-wave writes, own-wave reads
    {
        float* hz = (float*)Sh;
        for (int i = l; i < NPW * 132; i += 64) hz[i] = 0.f;
    }

    s16x8 ahi[4], alo[4];     // h A-frags (row lr, k = kc*32+lg*8+j); h(t=0)=0
    #pragma unroll
    for (int kc = 0; kc < 4; ++kc){ ahi[kc] = (s16x8)0; alo[kc] = (s16x8)0; }
    s16x8 xhi[4], xlo[4];
    s16x8 rhhi[4], rhlo[4];

    #pragma unroll 1
    for (int t = 0; t < Rr; ++t){
        __syncthreads();   // t=0: bias init visible; also keeps waves aligned for L1 B-reuse

        // ---- output-row ranges ----
        if (l < NPW){
            int n = n0 + l, lo = 0, hi = 0;
            if (n < N){
                int F = (n * Rr + t) * Ll;
                lo = lower_bound_i32(valid_idx, nv, F);
                hi = lower_bound_i32(valid_idx, nv, F + Ll);
            }
            loL[l] = lo; hiL[l] = hi;
        }

        // ---- x A-frags (node = n0+lr, clamped; OOB rows never stored) ----
        {
            int nn = n0 + lr; if (nn > N - 1) nn = N - 1;
            const float* xp = x_rank + ((size_t)nn * Rr + t) * Hd;
            #pragma unroll
            for (int kc = 0; kc < 4; ++kc)
                split8(xp + kc * 32 + lg * 8, xhi[kc], xlo[kc]);
        }
        __builtin_amdgcn_sched_barrier(0);

        // ---- Phase R: ar = h@r_whh + x@r_wxh ; Sr = sigmoid(ar+rb) * h ----
        #pragma unroll
        for (int nc = 0; nc < 8; ++nc){
            f32x4 ar = (f32x4){0.f, 0.f, 0.f, 0.f};
            #pragma unroll
            for (int kc = 0; kc < 4; ++kc){
                s16x8 b0 = BFRAG(0, kc, nc);
                MM2(ar, ahi[kc], alo[kc], b0);
                s16x8 b2 = BFRAG(2, kc, nc);
                MM2(ar, xhi[kc], xlo[kc], b2);
            }
            const float rbc = bias_s[0][nc * 16 + lr];
            #pragma unroll
            for (int i = 0; i < 4; ++i){
                const int row = lg * 4 + i, col = nc * 16 + lr;
                float r = 1.f / (1.f + __expf(-(ar[i] + rbc)));
                Sr[row][col] = r * Sh[row][col];
            }
            if (nc & 1) __builtin_amdgcn_sched_barrier(0);
        }

        // ---- (r*h) A-frags (same-wave LDS in-order: R-phase writes visible) ----
        #pragma unroll
        for (int kc = 0; kc < 4; ++kc)
            split8(&Sr[lr][kc * 32 + lg * 8], rhhi[kc], rhlo[kc]);
        __builtin_amdgcn_sched_barrier(0);

        // ---- Phase C: ac = (r*h)@c_whh + x@c_wxh ; Sr <- tanh(ac+cb) (overwrite rh) ----
        #pragma unroll
        for (int nc = 0; nc < 8; ++nc){
            f32x4 ac = (f32x4){0.f, 0.f, 0.f, 0.f};
            #pragma unroll
            for (int kc = 0; kc < 4; ++kc){
                s16x8 b4 = BFRAG(4, kc, nc);
                MM2(ac, rhhi[kc], rhlo[kc], b4);
                s16x8 b5 = BFRAG(5, kc, nc);
                MM2(ac, xhi[kc], xlo[kc], b5);
            }
            const float cbc = bias_s[2][nc * 16 + lr];
            #pragma unroll
            for (int i = 0; i < 4; ++i){
                const int row = lg * 4 + i, col = nc * 16 + lr;
                float e = __expf(2.f * (ac[i] + cbc));
                Sr[row][col] = 1.f - 2.f / (e + 1.f);   // tanh, saturates correctly
            }
            if (nc & 1) __builtin_amdgcn_sched_barrier(0);
        }

        // ---- Phase Z: az = h@u_whh + x@u_wxh ; h' = h + sigmoid(az+ub)*(c - h) ----
        #pragma unroll
        for (int nc = 0; nc < 8; ++nc){
            f32x4 az = (f32x4){0.f, 0.f, 0.f, 0.f};
            #pragma unroll
            for (int kc = 0; kc < 4; ++kc){
                s16x8 b1 = BFRAG(1, kc, nc);
                MM2(az, ahi[kc], alo[kc], b1);
                s16x8 b3 = BFRAG(3, kc, nc);
                MM2(az, xhi[kc], xlo[kc], b3);
            }
            const float ubc = bias_s[1][nc * 16 + lr];
            #pragma unroll
            for (int i = 0; i < 4; ++i){
                const int row = lg * 4 + i, col = nc * 16 + lr;
                float z  = 1.f / (1.f + __expf(-(az[i] + ubc)));
                float ho = Sh[row][col];
                float cc = Sr[row][col];
                Sh[row][col] = ho + z * (cc - ho);
            }
            if (nc & 1) __builtin_amdgcn_sched_barrier(0);
        }

        // ---- h' A-frags: serve Phase O now AND Phase R of next t ----
        #pragma unroll
        for (int kc = 0; kc < 4; ++kc)
            split8(&Sh[lr][kc * 32 + lg * 8], ahi[kc], alo[kc]);
        __builtin_amdgcn_sched_barrier(0);

        // ---- Phase O: ao = h'@McT + bc -> stage full rows in Sr ----
        #pragma unroll
        for (int nc = 0; nc < 8; ++nc){
            f32x4 ao = (f32x4){0.f, 0.f, 0.f, 0.f};
            #pragma unroll
            for (int kc = 0; kc < 4; ++kc){
                s16x8 b6 = BFRAG(6, kc, nc);
                MM2(ao, ahi[kc], alo[kc], b6);
            }
            const float obc = bias_s[3][nc * 16 + lr];
            #pragma unroll
            for (int i = 0; i < 4; ++i)
                Sr[lg * 4 + i][nc * 16 + lr] = ao[i] + obc;
            if (nc & 1) __builtin_amdgcn_sched_barrier(0);
        }
        __builtin_amdgcn_sched_barrier(0);

        // ---- epilogue: full-line coalesced stores with run replication ----
        // 32 lanes cover one 512-B row; lanes 0-31 -> row m*2, lanes 32-63 -> row m*2+1
        #pragma unroll
        for (int m = 0; m < 8; ++m){
            const int row = m * 2 + (l >> 5);
            const int c4  = (l & 31) * 4;
            const float4 v = *(const float4*)&Sr[row][c4];
            const int lo = loL[row], hi = hiL[row];
            for (int rr = lo; rr < hi; ++rr)
                *(float4*)(out + (size_t)rr * Hd + c4) = v;
        }
    }
}

__global__ void he_order_kernel(const int* __restrict__ he_order,
                                float* __restrict__ out_tail, int nv)
{
    const int i = blockIdx.x * 256 + threadIdx.x;
    if (i < nv) out_tail[i] = (float)he_order[i];
}

extern "C" void kernel_launch(void* const* d_in, const int* in_sizes, int n_in,
                              void* d_out, int out_size, void* d_ws, size_t ws_size,
                              hipStream_t stream)
{
    const float* x_rank    = (const float*)d_in[0];
    // d_in[1] he_features, d_in[2] he_idx: dead (softmax over singleton axis == 1)
    const int*   valid_idx = (const int*)d_in[3];
    const int*   he_order  = (const int*)d_in[4];
    const float* r_whh = (const float*)d_in[5];
    const float* r_wxh = (const float*)d_in[6];
    const float* r_b   = (const float*)d_in[7];
    const float* u_whh = (const float*)d_in[8];
    const float* u_wxh = (const float*)d_in[9];
    const float* u_b   = (const float*)d_in[10];
    const float* c_whh = (const float*)d_in[11];
    const float* c_wxh = (const float*)d_in[12];
    const float* c_b   = (const float*)d_in[13];
    const float* in_proj_w = (const float*)d_in[14];
    const float* in_proj_b = (const float*)d_in[15];
    const float* out_w     = (const float*)d_in[16];
    const float* out_b     = (const float*)d_in[17];

    const int nv = in_sizes[3];
    const int N  = in_sizes[0] / (Rr * Hd);

    // workspace layout
    float* McT = (float*)d_ws;                         // 16384 f32
    float* bc  = McT + Hd * Hd;                        // 128 f32
    unsigned short* whi = (unsigned short*)(bc + Hd);  // 7*16384 u16

    float* out_f    = (float*)d_out;
    float* out_tail = out_f + (size_t)nv * Hd;

    fold_proj_kernel<<<Hd, Hd, 0, stream>>>(in_proj_w, in_proj_b, out_w, out_b, McT, bc);
    pack_kernel<<<dim3(32, 7), 64, 0, stream>>>(r_whh, u_whh, r_wxh, u_wxh, c_whh, c_wxh,
                                                McT, whi);

    const int nodes_per_block = 4 * NPW;  // 64
    const int nblocks = (N + nodes_per_block - 1) / nodes_per_block;  // 469
    gru_mfma_kernel<<<nblocks, 256, 0, stream>>>(
        x_rank, valid_idx, nv, r_b, u_b, c_b, whi, bc, out_f, N);

    he_order_kernel<<<(nv + 255) / 256, 256, 0, stream>>>(he_order, out_tail, nv);
}

// Round 7
// 153.854 us; speedup vs baseline: 7.5933x; 2.9446x over previous
//
#include <hip/hip_runtime.h>
#include <math.h>

#define Hd 128
#define Rr 3
#define Ll 4
#define NPW 16   // nodes (M-rows) per wave

typedef float f32x4 __attribute__((ext_vector_type(4)));
typedef short s16x8 __attribute__((ext_vector_type(8)));

__device__ __forceinline__ unsigned short f2bf(float f){
    unsigned u = __float_as_uint(f);
    return (unsigned short)((u + 0x7FFFu + ((u >> 16) & 1u)) >> 16);
}
__device__ __forceinline__ float bf2f(unsigned short h){
    return __uint_as_float(((unsigned)h) << 16);
}
__device__ __forceinline__ void split8(const float* p, s16x8& hi, s16x8& lo){
    float4 a = *(const float4*)p;
    float4 b = *(const float4*)(p + 4);
    float v[8] = {a.x, a.y, a.z, a.w, b.x, b.y, b.z, b.w};
    #pragma unroll
    for (int j = 0; j < 8; ++j){
        unsigned short h = f2bf(v[j]);
        hi[j] = (short)h;
        lo[j] = (short)f2bf(v[j] - bf2f(h));
    }
}
__device__ __forceinline__ int lower_bound_i32(const int* __restrict__ a, int n, int key){
    int lo = 0, hi = n;
    while (lo < hi){
        int mid = (lo + hi) >> 1;
        if (a[mid] < key) lo = mid + 1; else hi = mid;
    }
    return lo;
}

// async global->LDS, 16B per lane; LDS dest = uniform base + lane*16
__device__ __forceinline__ void gload_lds16(const unsigned short* g, unsigned short* l){
    __builtin_amdgcn_global_load_lds(
        (const __attribute__((address_space(1))) void*)g,
        (__attribute__((address_space(3))) void*)l, 16, 0, 0);
}

// ---- McT = out_w @ wv (folded), bc = out_w @ bv + out_b  (verified r1-r6) ----
__global__ void fold_proj_kernel(const float* __restrict__ in_proj_w,
                                 const float* __restrict__ in_proj_b,
                                 const float* __restrict__ out_w,
                                 const float* __restrict__ out_b,
                                 float* __restrict__ McT,
                                 float* __restrict__ bc)
{
    const int i = blockIdx.x;   // k index
    const int j = threadIdx.x;  // n index
    float acc = 0.f;
    for (int k = 0; k < Hd; ++k)
        acc = fmaf(out_w[j * Hd + k], in_proj_w[(2 * Hd + k) * Hd + i], acc);
    McT[i * Hd + j] = acc;
    if (i == 0){
        float b = out_b[j];
        for (int k = 0; k < Hd; ++k)
            b = fmaf(out_w[j * Hd + k], in_proj_b[2 * Hd + k], b);
        bc[j] = b;
    }
}

// ---- quantize weights to bf16 MFMA B-fragments (verified r4-r6) ----
// frag elem j of lane l at (mat,kc,nc):  W[kc*32 + (l>>4)*8 + j][nc*16 + (l&15)]
__global__ void pack_kernel(const float* __restrict__ r_whh, const float* __restrict__ u_whh,
                            const float* __restrict__ r_wxh, const float* __restrict__ u_wxh,
                            const float* __restrict__ c_whh, const float* __restrict__ c_wxh,
                            const float* __restrict__ McT,
                            unsigned short* __restrict__ whi)
{
    const int mat  = blockIdx.y;   // 0..6
    const int tile = blockIdx.x;   // 0..31 : kc = tile>>3, nc = tile&7
    const int l    = threadIdx.x;  // 0..63
    const float* W;
    switch (mat){
        case 0: W = r_whh; break;  case 1: W = u_whh; break;
        case 2: W = r_wxh; break;  case 3: W = u_wxh; break;
        case 4: W = c_whh; break;  case 5: W = c_wxh; break;
        default: W = McT;
    }
    const int kc = tile >> 3, nc = tile & 7;
    const int kbase = kc * 32 + (l >> 4) * 8;
    const int n = nc * 16 + (l & 15);
    const size_t obase = ((size_t)(mat * 32 + tile) * 64 + l) * 8;
    #pragma unroll
    for (int j = 0; j < 8; ++j)
        whi[obase + j] = f2bf(W[(kbase + j) * Hd + n]);
}

// B-frag read from LDS weight buffer (ds_read_b128, contiguous per wave)
#define BF_LDS(kc, nc) (*(const s16x8*)&WL[(((kc) * 8 + (nc)) * 64 + l) * 8])

#define MM2(acc, AH, AL, BH)                                              \
    acc = __builtin_amdgcn_mfma_f32_16x16x32_bf16(AH, BH, acc, 0, 0, 0);  \
    acc = __builtin_amdgcn_mfma_f32_16x16x32_bf16(AL, BH, acc, 0, 0, 0);

__global__ __launch_bounds__(256, 1) void gru_mfma_kernel(
    const float* __restrict__ x_rank,
    const int* __restrict__ valid_idx, int nv,
    const float* __restrict__ r_b, const float* __restrict__ u_b, const float* __restrict__ c_b,
    const unsigned short* __restrict__ whi,
    const float* __restrict__ bc,
    float* __restrict__ out, int N)
{
    // per-wave multi-purpose scratch: rh-transpose -> h'-transpose -> out staging
    __shared__ __align__(16) float Sr_all[4][NPW][132];
    // block-shared weight stage buffer (one 128x128 bf16 matrix = 32 KB)
    __shared__ __align__(16) unsigned short WL[16384];
    __shared__ float bias_s[4][Hd];
    __shared__ int lo_all[4][NPW];
    __shared__ int hi_all[4][NPW];

    const int tid = threadIdx.x;
    const int wid = tid >> 6;
    const int l   = tid & 63;
    const int lr  = l & 15;
    const int lg  = l >> 4;
    const int n0  = (blockIdx.x * 4 + wid) * NPW;

    float (*Sr)[132] = Sr_all[wid];
    int* loL = lo_all[wid];
    int* hiL = hi_all[wid];

    if (tid < Hd){
        bias_s[0][tid] = r_b[tid];
        bias_s[1][tid] = u_b[tid];
        bias_s[2][tid] = c_b[tid];
        bias_s[3][tid] = bc[tid];
    }

    // stage one matrix: 32 chunks of 1 KB; wave w covers chunks {8i+... } = it*4+w
    #define STAGE_MAT(mat)                                                       \
        {                                                                        \
            const unsigned short* msrc = whi + (size_t)(mat) * 16384;            \
            _Pragma("unroll")                                                    \
            for (int it = 0; it < 8; ++it){                                      \
                const int chunk = it * 4 + wid;                                  \
                gload_lds16(msrc + chunk * 512 + l * 8, &WL[chunk * 512]);       \
            }                                                                    \
        }

    // persistent register state
    f32x4 hD[8];              // h in D-layout: row lg*4+i, col nc*16+lr
    s16x8 ahi[4], alo[4];     // h A-frags (row lr, k = kc*32+lg*8+j); h(t=0)=0
    #pragma unroll
    for (int nc = 0; nc < 8; ++nc) hD[nc] = (f32x4){0.f, 0.f, 0.f, 0.f};
    #pragma unroll
    for (int kc = 0; kc < 4; ++kc){ ahi[kc] = (s16x8)0; alo[kc] = (s16x8)0; }

    s16x8 xhi[4], xlo[4];
    s16x8 rhhi[4], rhlo[4];

    #pragma unroll 1
    for (int t = 0; t < Rr; ++t){
        // ---- output-row ranges ----
        if (l < NPW){
            int n = n0 + l, lo = 0, hi = 0;
            if (n < N){
                int F = (n * Rr + t) * Ll;
                lo = lower_bound_i32(valid_idx, nv, F);
                hi = lower_bound_i32(valid_idx, nv, F + Ll);
            }
            loL[l] = lo; hiL[l] = hi;
        }

        // ---- x A-frags (node = n0+lr, clamped; OOB rows never stored) ----
        {
            int nn = n0 + lr; if (nn > N - 1) nn = N - 1;
            const float* xp = x_rank + ((size_t)nn * Rr + t) * Hd;
            #pragma unroll
            for (int kc = 0; kc < 4; ++kc)
                split8(xp + kc * 32 + lg * 8, xhi[kc], xlo[kc]);
        }

        f32x4 accR[8], accZ[8];

        // ==== S1: r_whh -> accR = h @ W ====
        __syncthreads();                 // prior WL readers done
        STAGE_MAT(0);
        __syncthreads();                 // vmcnt drained: WL ready
        #pragma unroll
        for (int nc = 0; nc < 8; ++nc){
            accR[nc] = (f32x4){0.f, 0.f, 0.f, 0.f};
            #pragma unroll
            for (int kc = 0; kc < 4; ++kc){ s16x8 b = BF_LDS(kc, nc); MM2(accR[nc], ahi[kc], alo[kc], b); }
            if (nc & 1) __builtin_amdgcn_sched_barrier(0);
        }

        // ==== S2: r_wxh -> accR += x @ W ; Sr = sigmoid(accR+rb) * h ====
        __syncthreads();
        STAGE_MAT(2);
        __syncthreads();
        #pragma unroll
        for (int nc = 0; nc < 8; ++nc){
            #pragma unroll
            for (int kc = 0; kc < 4; ++kc){ s16x8 b = BF_LDS(kc, nc); MM2(accR[nc], xhi[kc], xlo[kc], b); }
            const float rbc = bias_s[0][nc * 16 + lr];
            #pragma unroll
            for (int i = 0; i < 4; ++i){
                float r = 1.f / (1.f + __expf(-(accR[nc][i] + rbc)));
                Sr[lg * 4 + i][nc * 16 + lr] = r * hD[nc][i];
            }
            if (nc & 1) __builtin_amdgcn_sched_barrier(0);
        }

        // ==== S3: u_whh -> accZ = h @ W  (h-frags die after) ====
        __syncthreads();
        STAGE_MAT(1);
        __syncthreads();
        #pragma unroll
        for (int nc = 0; nc < 8; ++nc){
            accZ[nc] = (f32x4){0.f, 0.f, 0.f, 0.f};
            #pragma unroll
            for (int kc = 0; kc < 4; ++kc){ s16x8 b = BF_LDS(kc, nc); MM2(accZ[nc], ahi[kc], alo[kc], b); }
            if (nc & 1) __builtin_amdgcn_sched_barrier(0);
        }

        // ==== S4: u_wxh -> accZ += x @ W ; z = sigmoid(accZ+ub) (kept in accZ) ====
        __syncthreads();
        STAGE_MAT(3);
        __syncthreads();
        #pragma unroll
        for (int nc = 0; nc < 8; ++nc){
            #pragma unroll
            for (int kc = 0; kc < 4; ++kc){ s16x8 b = BF_LDS(kc, nc); MM2(accZ[nc], xhi[kc], xlo[kc], b); }
            const float ubc = bias_s[1][nc * 16 + lr];
            #pragma unroll
            for (int i = 0; i < 4; ++i)
                accZ[nc][i] = 1.f / (1.f + __expf(-(accZ[nc][i] + ubc)));
            if (nc & 1) __builtin_amdgcn_sched_barrier(0);
        }

        // ==== S5: c_whh -> accC = (r*h) @ W ====
        __syncthreads();
        // rh A-frags from Sr (same-wave in-order; overlaps with staging below)
        #pragma unroll
        for (int kc = 0; kc < 4; ++kc)
            split8(&Sr[lr][kc * 32 + lg * 8], rhhi[kc], rhlo[kc]);
        STAGE_MAT(4);
        __syncthreads();
        f32x4 accC[8];
        #pragma unroll
        for (int nc = 0; nc < 8; ++nc){
            accC[nc] = (f32x4){0.f, 0.f, 0.f, 0.f};
            #pragma unroll
            for (int kc = 0; kc < 4; ++kc){ s16x8 b = BF_LDS(kc, nc); MM2(accC[nc], rhhi[kc], rhlo[kc], b); }
            if (nc & 1) __builtin_amdgcn_sched_barrier(0);
        }

        // ==== S6: c_wxh -> accC += x @ W ; h' = h + z*(tanh(accC+cb)-h) ; Sr = h' ====
        __syncthreads();
        STAGE_MAT(5);
        __syncthreads();
        #pragma unroll
        for (int nc = 0; nc < 8; ++nc){
            #pragma unroll
            for (int kc = 0; kc < 4; ++kc){ s16x8 b = BF_LDS(kc, nc); MM2(accC[nc], xhi[kc], xlo[kc], b); }
            const float cbc = bias_s[2][nc * 16 + lr];
            #pragma unroll
            for (int i = 0; i < 4; ++i){
                float e = __expf(2.f * (accC[nc][i] + cbc));
                float c = 1.f - 2.f / (e + 1.f);     // tanh, saturates correctly
                float ho = hD[nc][i];
                float hn = ho + accZ[nc][i] * (c - ho);
                hD[nc][i] = hn;
                Sr[lg * 4 + i][nc * 16 + lr] = hn;
            }
            if (nc & 1) __builtin_amdgcn_sched_barrier(0);
        }
        // h' A-frags: serve S7 now AND S1 of next t
        #pragma unroll
        for (int kc = 0; kc < 4; ++kc)
            split8(&Sr[lr][kc * 32 + lg * 8], ahi[kc], alo[kc]);

        // ==== S7: McT -> out rows staged in Sr, then coalesced scatter ====
        __syncthreads();
        STAGE_MAT(6);
        __syncthreads();
        #pragma unroll
        for (int nc = 0; nc < 8; ++nc){
            f32x4 ao = (f32x4){0.f, 0.f, 0.f, 0.f};
            #pragma unroll
            for (int kc = 0; kc < 4; ++kc){ s16x8 b = BF_LDS(kc, nc); MM2(ao, ahi[kc], alo[kc], b); }
            const float obc = bias_s[3][nc * 16 + lr];
            #pragma unroll
            for (int i = 0; i < 4; ++i)
                Sr[lg * 4 + i][nc * 16 + lr] = ao[i] + obc;
            if (nc & 1) __builtin_amdgcn_sched_barrier(0);
        }
        __builtin_amdgcn_sched_barrier(0);

        // epilogue: 32 lanes emit one full 512-B row; run replication via loL/hiL
        #pragma unroll
        for (int m = 0; m < 8; ++m){
            const int row = m * 2 + (l >> 5);
            const int c4  = (l & 31) * 4;
            const float4 v = *(const float4*)&Sr[row][c4];
            const int lo = loL[row], hi = hiL[row];
            for (int rr = lo; rr < hi; ++rr)
                *(float4*)(out + (size_t)rr * Hd + c4) = v;
        }
    }
    #undef STAGE_MAT
}

__global__ void he_order_kernel(const int* __restrict__ he_order,
                                float* __restrict__ out_tail, int nv)
{
    const int i = blockIdx.x * 256 + threadIdx.x;
    if (i < nv) out_tail[i] = (float)he_order[i];
}

extern "C" void kernel_launch(void* const* d_in, const int* in_sizes, int n_in,
                              void* d_out, int out_size, void* d_ws, size_t ws_size,
                              hipStream_t stream)
{
    const float* x_rank    = (const float*)d_in[0];
    // d_in[1] he_features, d_in[2] he_idx: dead (softmax over singleton axis == 1)
    const int*   valid_idx = (const int*)d_in[3];
    const int*   he_order  = (const int*)d_in[4];
    const float* r_whh = (const float*)d_in[5];
    const float* r_wxh = (const float*)d_in[6];
    const float* r_b   = (const float*)d_in[7];
    const float* u_whh = (const float*)d_in[8];
    const float* u_wxh = (const float*)d_in[9];
    const float* u_b   = (const float*)d_in[10];
    const float* c_whh = (const float*)d_in[11];
    const float* c_wxh = (const float*)d_in[12];
    const float* c_b   = (const float*)d_in[13];
    const float* in_proj_w = (const float*)d_in[14];
    const float* in_proj_b = (const float*)d_in[15];
    const float* out_w     = (const float*)d_in[16];
    const float* out_b     = (const float*)d_in[17];

    const int nv = in_sizes[3];
    const int N  = in_sizes[0] / (Rr * Hd);

    // workspace layout
    float* McT = (float*)d_ws;                         // 16384 f32
    float* bc  = McT + Hd * Hd;                        // 128 f32
    unsigned short* whi = (unsigned short*)(bc + Hd);  // 7*16384 u16

    float* out_f    = (float*)d_out;
    float* out_tail = out_f + (size_t)nv * Hd;

    fold_proj_kernel<<<Hd, Hd, 0, stream>>>(in_proj_w, in_proj_b, out_w, out_b, McT, bc);
    pack_kernel<<<dim3(32, 7), 64, 0, stream>>>(r_whh, u_whh, r_wxh, u_wxh, c_whh, c_wxh,
                                                McT, whi);

    const int nodes_per_block = 4 * NPW;  // 64
    const int nblocks = (N + nodes_per_block - 1) / nodes_per_block;  // 469
    gru_mfma_kernel<<<nblocks, 256, 0, stream>>>(
        x_rank, valid_idx, nv, r_b, u_b, c_b, whi, bc, out_f, N);

    he_order_kernel<<<(nv + 255) / 256, 256, 0, stream>>>(he_order, out_tail, nv);
}

// Round 8
// 111.798 us; speedup vs baseline: 10.4498x; 1.3762x over previous
//
#include <hip/hip_runtime.h>
#include <math.h>

#define Hd 128
#define Rr 3
#define Ll 4
#define NPW 16   // nodes (M-rows) per wave
#define NW  8    // waves per block

typedef float f32x4 __attribute__((ext_vector_type(4)));
typedef short s16x8 __attribute__((ext_vector_type(8)));

__device__ __forceinline__ unsigned short f2bf(float f){
    unsigned u = __float_as_uint(f);
    return (unsigned short)((u + 0x7FFFu + ((u >> 16) & 1u)) >> 16);
}
__device__ __forceinline__ float bf2f(unsigned short h){
    return __uint_as_float(((unsigned)h) << 16);
}
__device__ __forceinline__ void split8(const float* p, s16x8& hi, s16x8& lo){
    float4 a = *(const float4*)p;
    float4 b = *(const float4*)(p + 4);
    float v[8] = {a.x, a.y, a.z, a.w, b.x, b.y, b.z, b.w};
    #pragma unroll
    for (int j = 0; j < 8; ++j){
        unsigned short h = f2bf(v[j]);
        hi[j] = (short)h;
        lo[j] = (short)f2bf(v[j] - bf2f(h));
    }
}
__device__ __forceinline__ int lower_bound_i32(const int* __restrict__ a, int n, int key){
    int lo = 0, hi = n;
    while (lo < hi){
        int mid = (lo + hi) >> 1;
        if (a[mid] < key) lo = mid + 1; else hi = mid;
    }
    return lo;
}

// async global->LDS, 16B per lane; LDS dest = uniform base + lane*16
__device__ __forceinline__ void gload_lds16(const unsigned short* g, unsigned short* l){
    __builtin_amdgcn_global_load_lds(
        (const __attribute__((address_space(1))) void*)g,
        (__attribute__((address_space(3))) void*)l, 16, 0, 0);
}

// ---- McT = out_w @ wv (folded), bc = out_w @ bv + out_b  (verified r1-r7) ----
__global__ void fold_proj_kernel(const float* __restrict__ in_proj_w,
                                 const float* __restrict__ in_proj_b,
                                 const float* __restrict__ out_w,
                                 const float* __restrict__ out_b,
                                 float* __restrict__ McT,
                                 float* __restrict__ bc)
{
    const int i = blockIdx.x;   // k index
    const int j = threadIdx.x;  // n index
    float acc = 0.f;
    for (int k = 0; k < Hd; ++k)
        acc = fmaf(out_w[j * Hd + k], in_proj_w[(2 * Hd + k) * Hd + i], acc);
    McT[i * Hd + j] = acc;
    if (i == 0){
        float b = out_b[j];
        for (int k = 0; k < Hd; ++k)
            b = fmaf(out_w[j * Hd + k], in_proj_b[2 * Hd + k], b);
        bc[j] = b;
    }
}

// ---- quantize weights to bf16 MFMA B-fragments (verified r4-r7) ----
// frag elem j of lane l at (mat,kc,nc):  W[kc*32 + (l>>4)*8 + j][nc*16 + (l&15)]
__global__ void pack_kernel(const float* __restrict__ r_whh, const float* __restrict__ u_whh,
                            const float* __restrict__ r_wxh, const float* __restrict__ u_wxh,
                            const float* __restrict__ c_whh, const float* __restrict__ c_wxh,
                            const float* __restrict__ McT,
                            unsigned short* __restrict__ whi)
{
    const int mat  = blockIdx.y;   // 0..6
    const int tile = blockIdx.x;   // 0..31 : kc = tile>>3, nc = tile&7
    const int l    = threadIdx.x;  // 0..63
    const float* W;
    switch (mat){
        case 0: W = r_whh; break;  case 1: W = u_whh; break;
        case 2: W = r_wxh; break;  case 3: W = u_wxh; break;
        case 4: W = c_whh; break;  case 5: W = c_wxh; break;
        default: W = McT;
    }
    const int kc = tile >> 3, nc = tile & 7;
    const int kbase = kc * 32 + (l >> 4) * 8;
    const int n = nc * 16 + (l & 15);
    const size_t obase = ((size_t)(mat * 32 + tile) * 64 + l) * 8;
    #pragma unroll
    for (int j = 0; j < 8; ++j)
        whi[obase + j] = f2bf(W[(kbase + j) * Hd + n]);
}

// B-frag read from current LDS weight buffer (ds_read_b128, contiguous per wave)
#define BF_LDS(kc, nc) (*(const s16x8*)&WL[cur][(((kc) * 8 + (nc)) * 64 + l) * 8])

#define MM2(acc, AH, AL, BH)                                              \
    acc = __builtin_amdgcn_mfma_f32_16x16x32_bf16(AH, BH, acc, 0, 0, 0);  \
    acc = __builtin_amdgcn_mfma_f32_16x16x32_bf16(AL, BH, acc, 0, 0, 0);

__global__ __launch_bounds__(512, 1) void gru_mfma_kernel(
    const float* __restrict__ x_rank,
    const int* __restrict__ valid_idx, int nv,
    const float* __restrict__ r_b, const float* __restrict__ u_b, const float* __restrict__ c_b,
    const unsigned short* __restrict__ whi,
    const float* __restrict__ bc,
    float* __restrict__ out, int N)
{
    // double-buffered block-shared weight stage (2 x 32 KB)
    __shared__ __align__(16) unsigned short WL[2][16384];
    // per-wave multi-purpose scratch: rh-transpose -> h'-transpose -> out staging
    __shared__ __align__(16) float Sr_all[NW][NPW][132];
    __shared__ float bias_s[4][Hd];
    __shared__ int lo_all[NW][NPW];
    __shared__ int hi_all[NW][NPW];

    const int tid = threadIdx.x;
    const int wid = tid >> 6;
    const int l   = tid & 63;
    const int lr  = l & 15;
    const int lg  = l >> 4;
    const int n0  = (blockIdx.x * NW + wid) * NPW;

    float (*Sr)[132] = Sr_all[wid];
    int* loL = lo_all[wid];
    int* hiL = hi_all[wid];

    if (tid < Hd){
        bias_s[0][tid] = r_b[tid];
        bias_s[1][tid] = u_b[tid];
        bias_s[2][tid] = c_b[tid];
        bias_s[3][tid] = bc[tid];
    }

    // stage one 32KB matrix into buffer b: 32 chunks of 1KB, wave covers it*8+wid
    #define STAGE_MAT(mat, b)                                                    \
        {                                                                        \
            const unsigned short* msrc = whi + (size_t)(mat) * 16384;            \
            _Pragma("unroll")                                                    \
            for (int it = 0; it < 4; ++it){                                      \
                const int chunk = it * 8 + wid;                                  \
                gload_lds16(msrc + chunk * 512 + l * 8, &WL[b][chunk * 512]);    \
            }                                                                    \
        }

    // persistent register state
    f32x4 hD[8];              // h in D-layout: row lg*4+i, col nc*16+lr
    s16x8 ahi[4], alo[4];     // h A-frags (row lr, k = kc*32+lg*8+j); h(t=0)=0
    #pragma unroll
    for (int nc = 0; nc < 8; ++nc) hD[nc] = (f32x4){0.f, 0.f, 0.f, 0.f};
    #pragma unroll
    for (int kc = 0; kc < 4; ++kc){ ahi[kc] = (s16x8)0; alo[kc] = (s16x8)0; }

    s16x8 xhi[4], xlo[4];
    s16x8 rhhi[4], rhlo[4];

    unsigned cur = 0;
    STAGE_MAT(0, 0);          // prologue: r_whh into buf0

    #pragma unroll 1
    for (int t = 0; t < Rr; ++t){
        // ---- output-row ranges ----
        if (l < NPW){
            int n = n0 + l, lo = 0, hi = 0;
            if (n < N){
                int F = (n * Rr + t) * Ll;
                lo = lower_bound_i32(valid_idx, nv, F);
                hi = lower_bound_i32(valid_idx, nv, F + Ll);
            }
            loL[l] = lo; hiL[l] = hi;
        }

        // ---- x A-frags (node = n0+lr, clamped; OOB rows never stored) ----
        {
            int nn = n0 + lr; if (nn > N - 1) nn = N - 1;
            const float* xp = x_rank + ((size_t)nn * Rr + t) * Hd;
            #pragma unroll
            for (int kc = 0; kc < 4; ++kc)
                split8(xp + kc * 32 + lg * 8, xhi[kc], xlo[kc]);
        }

        f32x4 accR[8], accZ[8];

        // ==== S1: [r_whh ready] issue r_wxh; accR = h @ r_whh ====
        __syncthreads();
        STAGE_MAT(2, cur ^ 1);
        #pragma unroll
        for (int nc = 0; nc < 8; ++nc){
            accR[nc] = (f32x4){0.f, 0.f, 0.f, 0.f};
            #pragma unroll
            for (int kc = 0; kc < 4; ++kc){ s16x8 b = BF_LDS(kc, nc); MM2(accR[nc], ahi[kc], alo[kc], b); }
            if (nc & 1) __builtin_amdgcn_sched_barrier(0);
        }
        cur ^= 1;

        // ==== S2: [r_wxh ready] issue u_whh; accR += x @ r_wxh ; Sr = r*h ====
        __syncthreads();
        STAGE_MAT(1, cur ^ 1);
        #pragma unroll
        for (int nc = 0; nc < 8; ++nc){
            #pragma unroll
            for (int kc = 0; kc < 4; ++kc){ s16x8 b = BF_LDS(kc, nc); MM2(accR[nc], xhi[kc], xlo[kc], b); }
            const float rbc = bias_s[0][nc * 16 + lr];
            #pragma unroll
            for (int i = 0; i < 4; ++i){
                float r = 1.f / (1.f + __expf(-(accR[nc][i] + rbc)));
                Sr[lg * 4 + i][nc * 16 + lr] = r * hD[nc][i];
            }
            if (nc & 1) __builtin_amdgcn_sched_barrier(0);
        }
        cur ^= 1;

        // ==== S3: [u_whh ready] issue u_wxh; accZ = h @ u_whh ====
        __syncthreads();
        STAGE_MAT(3, cur ^ 1);
        #pragma unroll
        for (int nc = 0; nc < 8; ++nc){
            accZ[nc] = (f32x4){0.f, 0.f, 0.f, 0.f};
            #pragma unroll
            for (int kc = 0; kc < 4; ++kc){ s16x8 b = BF_LDS(kc, nc); MM2(accZ[nc], ahi[kc], alo[kc], b); }
            if (nc & 1) __builtin_amdgcn_sched_barrier(0);
        }
        cur ^= 1;

        // ==== S4: [u_wxh ready] issue c_whh; accZ += x @ u_wxh ; z = sigmoid ====
        __syncthreads();
        STAGE_MAT(4, cur ^ 1);
        #pragma unroll
        for (int nc = 0; nc < 8; ++nc){
            #pragma unroll
            for (int kc = 0; kc < 4; ++kc){ s16x8 b = BF_LDS(kc, nc); MM2(accZ[nc], xhi[kc], xlo[kc], b); }
            const float ubc = bias_s[1][nc * 16 + lr];
            #pragma unroll
            for (int i = 0; i < 4; ++i)
                accZ[nc][i] = 1.f / (1.f + __expf(-(accZ[nc][i] + ubc)));
            if (nc & 1) __builtin_amdgcn_sched_barrier(0);
        }
        cur ^= 1;

        // ==== S5: [c_whh ready] issue c_wxh; rh frags; accC = (r*h) @ c_whh ====
        __syncthreads();
        STAGE_MAT(5, cur ^ 1);
        #pragma unroll
        for (int kc = 0; kc < 4; ++kc)
            split8(&Sr[lr][kc * 32 + lg * 8], rhhi[kc], rhlo[kc]);
        f32x4 accC[8];
        #pragma unroll
        for (int nc = 0; nc < 8; ++nc){
            accC[nc] = (f32x4){0.f, 0.f, 0.f, 0.f};
            #pragma unroll
            for (int kc = 0; kc < 4; ++kc){ s16x8 b = BF_LDS(kc, nc); MM2(accC[nc], rhhi[kc], rhlo[kc], b); }
            if (nc & 1) __builtin_amdgcn_sched_barrier(0);
        }
        cur ^= 1;

        // ==== S6: [c_wxh ready] issue McT; accC += x @ c_wxh ; h' update ; Sr = h' ====
        __syncthreads();
        STAGE_MAT(6, cur ^ 1);
        #pragma unroll
        for (int nc = 0; nc < 8; ++nc){
            #pragma unroll
            for (int kc = 0; kc < 4; ++kc){ s16x8 b = BF_LDS(kc, nc); MM2(accC[nc], xhi[kc], xlo[kc], b); }
            const float cbc = bias_s[2][nc * 16 + lr];
            #pragma unroll
            for (int i = 0; i < 4; ++i){
                float e = __expf(2.f * (accC[nc][i] + cbc));
                float c = 1.f - 2.f / (e + 1.f);     // tanh, saturates correctly
                float ho = hD[nc][i];
                float hn = ho + accZ[nc][i] * (c - ho);
                hD[nc][i] = hn;
                Sr[lg * 4 + i][nc * 16 + lr] = hn;
            }
            if (nc & 1) __builtin_amdgcn_sched_barrier(0);
        }
        // h' A-frags: serve S7 now AND S1 of next t
        #pragma unroll
        for (int kc = 0; kc < 4; ++kc)
            split8(&Sr[lr][kc * 32 + lg * 8], ahi[kc], alo[kc]);
        cur ^= 1;

        // ==== S7: [McT ready] issue r_whh (next t); out rows -> Sr; scatter ====
        __syncthreads();
        if (t < Rr - 1) STAGE_MAT(0, cur ^ 1);
        #pragma unroll
        for (int nc = 0; nc < 8; ++nc){
            f32x4 ao = (f32x4){0.f, 0.f, 0.f, 0.f};
            #pragma unroll
            for (int kc = 0; kc < 4; ++kc){ s16x8 b = BF_LDS(kc, nc); MM2(ao, ahi[kc], alo[kc], b); }
            const float obc = bias_s[3][nc * 16 + lr];
            #pragma unroll
            for (int i = 0; i < 4; ++i)
                Sr[lg * 4 + i][nc * 16 + lr] = ao[i] + obc;
            if (nc & 1) __builtin_amdgcn_sched_barrier(0);
        }
        __builtin_amdgcn_sched_barrier(0);

        // epilogue: 32 lanes emit one full 512-B row; run replication via loL/hiL
        #pragma unroll
        for (int m = 0; m < 8; ++m){
            const int row = m * 2 + (l >> 5);
            const int c4  = (l & 31) * 4;
            const float4 v = *(const float4*)&Sr[row][c4];
            const int lo = loL[row], hi = hiL[row];
            for (int rr = lo; rr < hi; ++rr)
                *(float4*)(out + (size_t)rr * Hd + c4) = v;
        }
        cur ^= 1;
    }
    #undef STAGE_MAT
}

__global__ void he_order_kernel(const int* __restrict__ he_order,
                                float* __restrict__ out_tail, int nv)
{
    const int i = blockIdx.x * 256 + threadIdx.x;
    if (i < nv) out_tail[i] = (float)he_order[i];
}

extern "C" void kernel_launch(void* const* d_in, const int* in_sizes, int n_in,
                              void* d_out, int out_size, void* d_ws, size_t ws_size,
                              hipStream_t stream)
{
    const float* x_rank    = (const float*)d_in[0];
    // d_in[1] he_features, d_in[2] he_idx: dead (softmax over singleton axis == 1)
    const int*   valid_idx = (const int*)d_in[3];
    const int*   he_order  = (const int*)d_in[4];
    const float* r_whh = (const float*)d_in[5];
    const float* r_wxh = (const float*)d_in[6];
    const float* r_b   = (const float*)d_in[7];
    const float* u_whh = (const float*)d_in[8];
    const float* u_wxh = (const float*)d_in[9];
    const float* u_b   = (const float*)d_in[10];
    const float* c_whh = (const float*)d_in[11];
    const float* c_wxh = (const float*)d_in[12];
    const float* c_b   = (const float*)d_in[13];
    const float* in_proj_w = (const float*)d_in[14];
    const float* in_proj_b = (const float*)d_in[15];
    const float* out_w     = (const float*)d_in[16];
    const float* out_b     = (const float*)d_in[17];

    const int nv = in_sizes[3];
    const int N  = in_sizes[0] / (Rr * Hd);

    // workspace layout
    float* McT = (float*)d_ws;                         // 16384 f32
    float* bc  = McT + Hd * Hd;                        // 128 f32
    unsigned short* whi = (unsigned short*)(bc + Hd);  // 7*16384 u16

    float* out_f    = (float*)d_out;
    float* out_tail = out_f + (size_t)nv * Hd;

    fold_proj_kernel<<<Hd, Hd, 0, stream>>>(in_proj_w, in_proj_b, out_w, out_b, McT, bc);
    pack_kernel<<<dim3(32, 7), 64, 0, stream>>>(r_whh, u_whh, r_wxh, u_wxh, c_whh, c_wxh,
                                                McT, whi);

    const int nodes_per_block = NW * NPW;  // 128
    const int nblocks = (N + nodes_per_block - 1) / nodes_per_block;  // 235
    gru_mfma_kernel<<<nblocks, 512, 0, stream>>>(
        x_rank, valid_idx, nv, r_b, u_b, c_b, whi, bc, out_f, N);

    he_order_kernel<<<(nv + 255) / 256, 256, 0, stream>>>(he_order, out_tail, nv);
}

// Round 9
// 97.282 us; speedup vs baseline: 12.0091x; 1.1492x over previous
//
#include <hip/hip_runtime.h>
#include <math.h>

#define Hd 128
#define Rr 3
#define Ll 4
#define NPW 16   // nodes (M-rows) per wave
#define NW  8    // waves per block

typedef float f32x4 __attribute__((ext_vector_type(4)));
typedef short s16x8 __attribute__((ext_vector_type(8)));

__device__ __forceinline__ unsigned short f2bf(float f){
    unsigned u = __float_as_uint(f);
    return (unsigned short)((u + 0x7FFFu + ((u >> 16) & 1u)) >> 16);
}
// convert 8 consecutive f32 -> bf16 A-fragment (hi plane only)
__device__ __forceinline__ s16x8 cvt8(const float* p){
    float4 a = *(const float4*)p;
    float4 b = *(const float4*)(p + 4);
    float v[8] = {a.x, a.y, a.z, a.w, b.x, b.y, b.z, b.w};
    s16x8 r;
    #pragma unroll
    for (int j = 0; j < 8; ++j) r[j] = (short)f2bf(v[j]);
    return r;
}
__device__ __forceinline__ int lower_bound_i32(const int* __restrict__ a, int n, int key){
    int lo = 0, hi = n;
    while (lo < hi){
        int mid = (lo + hi) >> 1;
        if (a[mid] < key) lo = mid + 1; else hi = mid;
    }
    return lo;
}

// async global->LDS, 16B per lane; LDS dest = uniform base + lane*16
__device__ __forceinline__ void gload_lds16(const unsigned short* g, unsigned short* l){
    __builtin_amdgcn_global_load_lds(
        (const __attribute__((address_space(1))) void*)g,
        (__attribute__((address_space(3))) void*)l, 16, 0, 0);
}

// ---- McT = out_w @ wv (folded), bc = out_w @ bv + out_b  (verified r1-r8) ----
__global__ void fold_proj_kernel(const float* __restrict__ in_proj_w,
                                 const float* __restrict__ in_proj_b,
                                 const float* __restrict__ out_w,
                                 const float* __restrict__ out_b,
                                 float* __restrict__ McT,
                                 float* __restrict__ bc)
{
    const int i = blockIdx.x;   // k index
    const int j = threadIdx.x;  // n index
    float acc = 0.f;
    for (int k = 0; k < Hd; ++k)
        acc = fmaf(out_w[j * Hd + k], in_proj_w[(2 * Hd + k) * Hd + i], acc);
    McT[i * Hd + j] = acc;
    if (i == 0){
        float b = out_b[j];
        for (int k = 0; k < Hd; ++k)
            b = fmaf(out_w[j * Hd + k], in_proj_b[2 * Hd + k], b);
        bc[j] = b;
    }
}

// ---- quantize weights to bf16 MFMA B-fragments (verified r4-r8) ----
// frag elem j of lane l at (mat,kc,nc):  W[kc*32 + (l>>4)*8 + j][nc*16 + (l&15)]
__global__ void pack_kernel(const float* __restrict__ r_whh, const float* __restrict__ u_whh,
                            const float* __restrict__ r_wxh, const float* __restrict__ u_wxh,
                            const float* __restrict__ c_whh, const float* __restrict__ c_wxh,
                            const float* __restrict__ McT,
                            unsigned short* __restrict__ whi)
{
    const int mat  = blockIdx.y;   // 0..6
    const int tile = blockIdx.x;   // 0..31 : kc = tile>>3, nc = tile&7
    const int l    = threadIdx.x;  // 0..63
    const float* W;
    switch (mat){
        case 0: W = r_whh; break;  case 1: W = u_whh; break;
        case 2: W = r_wxh; break;  case 3: W = u_wxh; break;
        case 4: W = c_whh; break;  case 5: W = c_wxh; break;
        default: W = McT;
    }
    const int kc = tile >> 3, nc = tile & 7;
    const int kbase = kc * 32 + (l >> 4) * 8;
    const int n = nc * 16 + (l & 15);
    const size_t obase = ((size_t)(mat * 32 + tile) * 64 + l) * 8;
    #pragma unroll
    for (int j = 0; j < 8; ++j)
        whi[obase + j] = f2bf(W[(kbase + j) * Hd + n]);
}

// B-frag read from current LDS weight buffer (ds_read_b128, contiguous per wave)
#define BF_LDS(kc, nc) (*(const s16x8*)&WL[cur][(((kc) * 8 + (nc)) * 64 + l) * 8])

#define MM1(acc, AH, BH)                                                  \
    acc = __builtin_amdgcn_mfma_f32_16x16x32_bf16(AH, BH, acc, 0, 0, 0);

__global__ __launch_bounds__(512, 1) void gru_mfma_kernel(
    const float* __restrict__ x_rank,
    const int* __restrict__ valid_idx, int nv,
    const float* __restrict__ r_b, const float* __restrict__ u_b, const float* __restrict__ c_b,
    const unsigned short* __restrict__ whi,
    const float* __restrict__ bc,
    float* __restrict__ out, int N)
{
    // double-buffered block-shared weight stage (2 x 32 KB)
    __shared__ __align__(16) unsigned short WL[2][16384];
    // per-wave multi-purpose scratch: rh-transpose -> h'-transpose -> out staging
    __shared__ __align__(16) float Sr_all[NW][NPW][132];
    __shared__ float bias_s[4][Hd];
    __shared__ int lo_all[NW][NPW];
    __shared__ int hi_all[NW][NPW];

    const int tid = threadIdx.x;
    const int wid = tid >> 6;
    const int l   = tid & 63;
    const int lr  = l & 15;
    const int lg  = l >> 4;
    const int n0  = (blockIdx.x * NW + wid) * NPW;

    float (*Sr)[132] = Sr_all[wid];
    int* loL = lo_all[wid];
    int* hiL = hi_all[wid];

    if (tid < Hd){
        bias_s[0][tid] = r_b[tid];
        bias_s[1][tid] = u_b[tid];
        bias_s[2][tid] = c_b[tid];
        bias_s[3][tid] = bc[tid];
    }

    // stage one 32KB matrix into buffer b: 32 chunks of 1KB, wave covers it*8+wid
    #define STAGE_MAT(mat, b)                                                    \
        {                                                                        \
            const unsigned short* msrc = whi + (size_t)(mat) * 16384;            \
            _Pragma("unroll")                                                    \
            for (int it = 0; it < 4; ++it){                                      \
                const int chunk = it * 8 + wid;                                  \
                gload_lds16(msrc + chunk * 512 + l * 8, &WL[b][chunk * 512]);    \
            }                                                                    \
        }

    // persistent register state
    f32x4 hD[8];              // h in D-layout: row lg*4+i, col nc*16+lr (exact f32 state)
    s16x8 ah[4];              // h A-frags bf16 (row lr, k = kc*32+lg*8+j); h(t=0)=0
    #pragma unroll
    for (int nc = 0; nc < 8; ++nc) hD[nc] = (f32x4){0.f, 0.f, 0.f, 0.f};
    #pragma unroll
    for (int kc = 0; kc < 4; ++kc) ah[kc] = (s16x8)0;

    s16x8 xh[4], rhh[4];

    unsigned cur = 0;
    STAGE_MAT(0, 0);          // prologue: r_whh into buf0

    #pragma unroll 1
    for (int t = 0; t < Rr; ++t){
        // ---- output-row ranges ----
        if (l < NPW){
            int n = n0 + l, lo = 0, hi = 0;
            if (n < N){
                int F = (n * Rr + t) * Ll;
                lo = lower_bound_i32(valid_idx, nv, F);
                hi = lower_bound_i32(valid_idx, nv, F + Ll);
            }
            loL[l] = lo; hiL[l] = hi;
        }

        // ---- x A-frags (node = n0+lr, clamped; OOB rows never stored) ----
        {
            int nn = n0 + lr; if (nn > N - 1) nn = N - 1;
            const float* xp = x_rank + ((size_t)nn * Rr + t) * Hd;
            #pragma unroll
            for (int kc = 0; kc < 4; ++kc)
                xh[kc] = cvt8(xp + kc * 32 + lg * 8);
        }

        f32x4 accR[8], accZ[8];

        // ==== S1: [r_whh ready] issue r_wxh; accR = h @ r_whh ====
        __syncthreads();
        STAGE_MAT(2, cur ^ 1);
        #pragma unroll
        for (int nc = 0; nc < 8; ++nc){
            accR[nc] = (f32x4){0.f, 0.f, 0.f, 0.f};
            #pragma unroll
            for (int kc = 0; kc < 4; ++kc){ s16x8 b = BF_LDS(kc, nc); MM1(accR[nc], ah[kc], b); }
            if ((nc & 3) == 3) __builtin_amdgcn_sched_barrier(0);
        }
        cur ^= 1;

        // ==== S2: [r_wxh ready] issue u_whh; accR += x @ r_wxh ; Sr = r*h ====
        __syncthreads();
        STAGE_MAT(1, cur ^ 1);
        #pragma unroll
        for (int nc = 0; nc < 8; ++nc){
            #pragma unroll
            for (int kc = 0; kc < 4; ++kc){ s16x8 b = BF_LDS(kc, nc); MM1(accR[nc], xh[kc], b); }
            const float rbc = bias_s[0][nc * 16 + lr];
            #pragma unroll
            for (int i = 0; i < 4; ++i){
                float r = 1.f / (1.f + __expf(-(accR[nc][i] + rbc)));
                Sr[lg * 4 + i][nc * 16 + lr] = r * hD[nc][i];
            }
            if ((nc & 3) == 3) __builtin_amdgcn_sched_barrier(0);
        }
        cur ^= 1;

        // ==== S3: [u_whh ready] issue u_wxh; accZ = h @ u_whh ====
        __syncthreads();
        STAGE_MAT(3, cur ^ 1);
        #pragma unroll
        for (int nc = 0; nc < 8; ++nc){
            accZ[nc] = (f32x4){0.f, 0.f, 0.f, 0.f};
            #pragma unroll
            for (int kc = 0; kc < 4; ++kc){ s16x8 b = BF_LDS(kc, nc); MM1(accZ[nc], ah[kc], b); }
            if ((nc & 3) == 3) __builtin_amdgcn_sched_barrier(0);
        }
        cur ^= 1;

        // ==== S4: [u_wxh ready] issue c_whh; accZ += x @ u_wxh ; z = sigmoid ====
        __syncthreads();
        STAGE_MAT(4, cur ^ 1);
        #pragma unroll
        for (int nc = 0; nc < 8; ++nc){
            #pragma unroll
            for (int kc = 0; kc < 4; ++kc){ s16x8 b = BF_LDS(kc, nc); MM1(accZ[nc], xh[kc], b); }
            const float ubc = bias_s[1][nc * 16 + lr];
            #pragma unroll
            for (int i = 0; i < 4; ++i)
                accZ[nc][i] = 1.f / (1.f + __expf(-(accZ[nc][i] + ubc)));
            if ((nc & 3) == 3) __builtin_amdgcn_sched_barrier(0);
        }
        cur ^= 1;

        // ==== S5: [c_whh ready] issue c_wxh; rh frags; accC = (r*h) @ c_whh ====
        __syncthreads();
        STAGE_MAT(5, cur ^ 1);
        #pragma unroll
        for (int kc = 0; kc < 4; ++kc)
            rhh[kc] = cvt8(&Sr[lr][kc * 32 + lg * 8]);
        f32x4 accC[8];
        #pragma unroll
        for (int nc = 0; nc < 8; ++nc){
            accC[nc] = (f32x4){0.f, 0.f, 0.f, 0.f};
            #pragma unroll
            for (int kc = 0; kc < 4; ++kc){ s16x8 b = BF_LDS(kc, nc); MM1(accC[nc], rhh[kc], b); }
            if ((nc & 3) == 3) __builtin_amdgcn_sched_barrier(0);
        }
        cur ^= 1;

        // ==== S6: [c_wxh ready] issue McT; accC += x @ c_wxh ; h' update ; Sr = h' ====
        __syncthreads();
        STAGE_MAT(6, cur ^ 1);
        #pragma unroll
        for (int nc = 0; nc < 8; ++nc){
            #pragma unroll
            for (int kc = 0; kc < 4; ++kc){ s16x8 b = BF_LDS(kc, nc); MM1(accC[nc], xh[kc], b); }
            const float cbc = bias_s[2][nc * 16 + lr];
            #pragma unroll
            for (int i = 0; i < 4; ++i){
                float e = __expf(2.f * (accC[nc][i] + cbc));
                float c = 1.f - 2.f / (e + 1.f);     // tanh, saturates correctly
                float ho = hD[nc][i];
                float hn = ho + accZ[nc][i] * (c - ho);
                hD[nc][i] = hn;
                Sr[lg * 4 + i][nc * 16 + lr] = hn;
            }
            if ((nc & 3) == 3) __builtin_amdgcn_sched_barrier(0);
        }
        // h' A-frags: serve S7 now AND S1 of next t
        #pragma unroll
        for (int kc = 0; kc < 4; ++kc)
            ah[kc] = cvt8(&Sr[lr][kc * 32 + lg * 8]);
        cur ^= 1;

        // ==== S7: [McT ready] issue r_whh (next t); out rows -> Sr; scatter ====
        __syncthreads();
        if (t < Rr - 1) STAGE_MAT(0, cur ^ 1);
        #pragma unroll
        for (int nc = 0; nc < 8; ++nc){
            f32x4 ao = (f32x4){0.f, 0.f, 0.f, 0.f};
            #pragma unroll
            for (int kc = 0; kc < 4; ++kc){ s16x8 b = BF_LDS(kc, nc); MM1(ao, ah[kc], b); }
            const float obc = bias_s[3][nc * 16 + lr];
            #pragma unroll
            for (int i = 0; i < 4; ++i)
                Sr[lg * 4 + i][nc * 16 + lr] = ao[i] + obc;
            if ((nc & 3) == 3) __builtin_amdgcn_sched_barrier(0);
        }
        __builtin_amdgcn_sched_barrier(0);

        // epilogue: 32 lanes emit one full 512-B row; run replication via loL/hiL
        #pragma unroll
        for (int m = 0; m < 8; ++m){
            const int row = m * 2 + (l >> 5);
            const int c4  = (l & 31) * 4;
            const float4 v = *(const float4*)&Sr[row][c4];
            const int lo = loL[row], hi = hiL[row];
            for (int rr = lo; rr < hi; ++rr)
                *(float4*)(out + (size_t)rr * Hd + c4) = v;
        }
        cur ^= 1;
    }
    #undef STAGE_MAT
}

__global__ void he_order_kernel(const int* __restrict__ he_order,
                                float* __restrict__ out_tail, int nv)
{
    const int i = blockIdx.x * 256 + threadIdx.x;
    if (i < nv) out_tail[i] = (float)he_order[i];
}

extern "C" void kernel_launch(void* const* d_in, const int* in_sizes, int n_in,
                              void* d_out, int out_size, void* d_ws, size_t ws_size,
                              hipStream_t stream)
{
    const float* x_rank    = (const float*)d_in[0];
    // d_in[1] he_features, d_in[2] he_idx: dead (softmax over singleton axis == 1)
    const int*   valid_idx = (const int*)d_in[3];
    const int*   he_order  = (const int*)d_in[4];
    const float* r_whh = (const float*)d_in[5];
    const float* r_wxh = (const float*)d_in[6];
    const float* r_b   = (const float*)d_in[7];
    const float* u_whh = (const float*)d_in[8];
    const float* u_wxh = (const float*)d_in[9];
    const float* u_b   = (const float*)d_in[10];
    const float* c_whh = (const float*)d_in[11];
    const float* c_wxh = (const float*)d_in[12];
    const float* c_b   = (const float*)d_in[13];
    const float* in_proj_w = (const float*)d_in[14];
    const float* in_proj_b = (const float*)d_in[15];
    const float* out_w     = (const float*)d_in[16];
    const float* out_b     = (const float*)d_in[17];

    const int nv = in_sizes[3];
    const int N  = in_sizes[0] / (Rr * Hd);

    // workspace layout
    float* McT = (float*)d_ws;                         // 16384 f32
    float* bc  = McT + Hd * Hd;                        // 128 f32
    unsigned short* whi = (unsigned short*)(bc + Hd);  // 7*16384 u16

    float* out_f    = (float*)d_out;
    float* out_tail = out_f + (size_t)nv * Hd;

    fold_proj_kernel<<<Hd, Hd, 0, stream>>>(in_proj_w, in_proj_b, out_w, out_b, McT, bc);
    pack_kernel<<<dim3(32, 7), 64, 0, stream>>>(r_whh, u_whh, r_wxh, u_wxh, c_whh, c_wxh,
                                                McT, whi);

    const int nodes_per_block = NW * NPW;  // 128
    const int nblocks = (N + nodes_per_block - 1) / nodes_per_block;  // 235
    gru_mfma_kernel<<<nblocks, 512, 0, stream>>>(
        x_rank, valid_idx, nv, r_b, u_b, c_b, whi, bc, out_f, N);

    he_order_kernel<<<(nv + 255) / 256, 256, 0, stream>>>(he_order, out_tail, nv);
}